// Round 1
// 866.996 us; speedup vs baseline: 1.0732x; 1.0732x over previous
//
#include <hip/hip_runtime.h>

typedef unsigned short u16;
typedef __attribute__((ext_vector_type(8))) short bf16x8;
typedef __attribute__((ext_vector_type(4))) float f32x4;

__device__ __forceinline__ u16 f2bf(float f) {
  union { float f; unsigned u; } v; v.f = f;
  unsigned u = v.u;
  u += 0x7fffu + ((u >> 16) & 1u);
  return (u16)(u >> 16);
}

__device__ __forceinline__ void gll16(const void* g, void* l) {
  __builtin_amdgcn_global_load_lds(
      (const __attribute__((address_space(1))) void*)g,
      (__attribute__((address_space(3))) void*)l, 16, 0, 0);
}

// ---------------------------------------------------------------------------
// P1: x[b][c][n] f32 -> xt[b][n][c] bf16   (C=512, N=1600), both inputs
// ---------------------------------------------------------------------------
__global__ __launch_bounds__(256) void transp_cast_x2(const float* __restrict__ ex,
                                                      const float* __restrict__ qu,
                                                      u16* __restrict__ xte,
                                                      u16* __restrict__ xtq) {
  __shared__ float t[32][33];
  int z = blockIdx.z;
  int b = z & 15;
  const float* xb = (z < 16 ? ex : qu) + (size_t)b * 819200;
  u16* xtb = (z < 16 ? xte : xtq) + (size_t)b * 819200;
  int n0 = blockIdx.x * 32, c0 = blockIdx.y * 32;
  int tx = threadIdx.x & 31, ty = threadIdx.x >> 5;
#pragma unroll
  for (int k = 0; k < 4; k++) {
    int c = ty + k * 8;
    t[c][tx] = xb[(size_t)(c0 + c) * 1600 + n0 + tx];
  }
  __syncthreads();
#pragma unroll
  for (int k = 0; k < 4; k++) {
    int n = ty + k * 8;
    xtb[(size_t)(n0 + n) * 512 + c0 + tx] = f2bf(t[tx][n]);
  }
}

// P2: cast w_e / w_q (256x512 each) to bf16
__global__ void cast_w(const float* __restrict__ we, const float* __restrict__ wq,
                       u16* __restrict__ oe, u16* __restrict__ oq) {
  int i = blockIdx.x * 256 + threadIdx.x;
  oe[i] = f2bf(we[i]);
  oq[i] = f2bf(wq[i]);
}

// P3: w[o][c][ky][kx] f32 -> wr[o][t*512+c] bf16 (both conv weights)
__global__ void repack_wc(const float* __restrict__ w1, const float* __restrict__ w2,
                          u16* __restrict__ o1, u16* __restrict__ o2) {
  const float* w = blockIdx.y ? w2 : w1;
  u16* wr = blockIdx.y ? o2 : o1;
  int idx = blockIdx.x * 256 + threadIdx.x;  // 2359296 total
  int o = idx / 4608;
  int r = idx - o * 4608;
  int t = r >> 9;
  int c = r & 511;
  wr[idx] = f2bf(w[o * 4608 + c * 9 + t]);
}

// P4: zero att buffers + Z buffers
__global__ void zero_mem(uint4* __restrict__ p, long n) {
  long i = (long)blockIdx.x * blockDim.x + threadIdx.x;
  long stride = (long)gridDim.x * blockDim.x;
  uint4 z; z.x = 0; z.y = 0; z.z = 0; z.w = 0;
  for (; i < n; i += stride) p[i] = z;
}

// ---------------------------------------------------------------------------
// Generic A*B^T bf16 GEMM, 128x128 tile, BK=64, XOR-swizzled LDS,
// dual problem sets selected by blockIdx.z (z<16 -> set1, else set2).
// MODE 0: store bf16 C[i*N+j].  MODE 2: store bf16 to padded pixel layout.
// ---------------------------------------------------------------------------
template <int MODE>
__global__ __launch_bounds__(256) void gemm_bt64(
    const u16* __restrict__ A, const u16* __restrict__ B, u16* __restrict__ C,
    const u16* __restrict__ A2, const u16* __restrict__ B2, u16* __restrict__ C2,
    int M, int N, int K, long sA, long sB, long sC) {
  __shared__ u16 lds_a[128 * 64];
  __shared__ u16 lds_b[128 * 64];
  int tid = threadIdx.x;
  int z = blockIdx.z, b = z & 15;
  const u16* Ab = (z < 16 ? A : A2) + (size_t)b * sA;
  const u16* Bb = (z < 16 ? B : B2) + (size_t)b * sB;
  u16* Cb = (z < 16 ? C : C2) + (size_t)b * sC;
  int m0 = blockIdx.x * 128, n0 = blockIdx.y * 128;

  int rsub = tid >> 3;                     // 0..31
  int gch = (tid & 7) ^ (rsub & 7);        // swizzled 16B chunk to fetch
  long Kb = (long)K * 2;
  const char* pa[4];
  const char* pb[4];
#pragma unroll
  for (int c = 0; c < 4; c++) {
    int ra = m0 + 32 * c + rsub; ra = ra < M ? ra : M - 1;
    int rb = n0 + 32 * c + rsub; rb = rb < N ? rb : N - 1;
    pa[c] = (const char*)Ab + (long)ra * Kb + gch * 16;
    pb[c] = (const char*)Bb + (long)rb * Kb + gch * 16;
  }

  const f32x4 fzero = {0.f, 0.f, 0.f, 0.f};
  f32x4 acc[4][4];
#pragma unroll
  for (int mi = 0; mi < 4; mi++)
#pragma unroll
    for (int ni = 0; ni < 4; ni++) acc[mi][ni] = fzero;

  int wid = tid >> 6, lane = tid & 63;
  int wm = wid & 1, wn = wid >> 1;
  int lrow = lane & 15, lquad = lane >> 4;
  int sl = lrow & 7;

  int ksteps = K >> 6;
  for (int ks = 0; ks < ksteps; ks++) {
#pragma unroll
    for (int c = 0; c < 4; c++) {
      gll16(pa[c], (char*)lds_a + c * 4096 + tid * 16);
      gll16(pb[c], (char*)lds_b + c * 4096 + tid * 16);
      pa[c] += 128; pb[c] += 128;
    }
    __syncthreads();
#pragma unroll
    for (int k2 = 0; k2 < 2; k2++) {
      int sel = ((k2 << 2) | lquad) ^ sl;
      bf16x8 bv[4];
#pragma unroll
      for (int ni = 0; ni < 4; ni++) {
        int rowb = wn * 64 + ni * 16 + lrow;
        bv[ni] = *(const bf16x8*)((const char*)lds_b + rowb * 128 + sel * 16);
      }
#pragma unroll
      for (int mi = 0; mi < 4; mi++) {
        int rowa = wm * 64 + mi * 16 + lrow;
        bf16x8 av = *(const bf16x8*)((const char*)lds_a + rowa * 128 + sel * 16);
#pragma unroll
        for (int ni = 0; ni < 4; ni++)
          acc[mi][ni] =
              __builtin_amdgcn_mfma_f32_16x16x32_bf16(av, bv[ni], acc[mi][ni], 0, 0, 0);
      }
    }
    __syncthreads();
  }

#pragma unroll
  for (int mi = 0; mi < 4; mi++) {
#pragma unroll
    for (int r = 0; r < 4; r++) {
      int i = m0 + wm * 64 + mi * 16 + lquad * 4 + r;
      if (i >= M) continue;
#pragma unroll
      for (int ni = 0; ni < 4; ni++) {
        int j = n0 + wn * 64 + ni * 16 + lrow;
        if (j >= N) continue;
        float v = acc[mi][ni][r];
        if (MODE == 2) {
          int y = i / 40, x = i - y * 40;
          Cb[(size_t)((y + 1) * 42 + (x + 1)) * 512 + j] = f2bf(v);
        } else {
          Cb[(size_t)i * N + j] = f2bf(v);
        }
      }
    }
  }
}

// ---------------------------------------------------------------------------
// K2: E = exp(ecorr * qcorr^T)  [1600x1600 per batch, K=256]
// Fused epilogue: E (coalesced 16B rows), ET (LDS transpose), Zrow/Zcol sums
// via shuffle + atomics.
// ---------------------------------------------------------------------------
__global__ __launch_bounds__(256) void gemm_corr_exp(
    const u16* __restrict__ A, const u16* __restrict__ B, u16* __restrict__ E,
    u16* __restrict__ ET, float* __restrict__ Zrow, float* __restrict__ Zcol) {
  __shared__ u16 lds_a[128 * 64];
  __shared__ u16 lds_b[128 * 64];
  int tid = threadIdx.x;
  int b = blockIdx.z;
  const u16* Ab = A + (size_t)b * 409600;
  const u16* Bb = B + (size_t)b * 409600;
  u16* Eb = E + (size_t)b * 2560000;
  u16* ETb = ET + (size_t)b * 2560000;
  int m0 = blockIdx.x * 128, n0 = blockIdx.y * 128;

  int rsub = tid >> 3;
  int gch = (tid & 7) ^ (rsub & 7);
  const char* pa[4];
  const char* pb[4];
#pragma unroll
  for (int c = 0; c < 4; c++) {
    int ra = m0 + 32 * c + rsub; ra = ra < 1600 ? ra : 1599;
    int rb = n0 + 32 * c + rsub; rb = rb < 1600 ? rb : 1599;
    pa[c] = (const char*)(Ab + (size_t)ra * 256) + gch * 16;
    pb[c] = (const char*)(Bb + (size_t)rb * 256) + gch * 16;
  }

  const f32x4 fzero = {0.f, 0.f, 0.f, 0.f};
  f32x4 acc[4][4];
#pragma unroll
  for (int mi = 0; mi < 4; mi++)
#pragma unroll
    for (int ni = 0; ni < 4; ni++) acc[mi][ni] = fzero;

  int wid = tid >> 6, lane = tid & 63;
  int wm = wid & 1, wn = wid >> 1;
  int lrow = lane & 15, lquad = lane >> 4;
  int sl = lrow & 7;

  for (int ks = 0; ks < 4; ks++) {
#pragma unroll
    for (int c = 0; c < 4; c++) {
      gll16(pa[c], (char*)lds_a + c * 4096 + tid * 16);
      gll16(pb[c], (char*)lds_b + c * 4096 + tid * 16);
      pa[c] += 128; pb[c] += 128;
    }
    __syncthreads();
#pragma unroll
    for (int k2 = 0; k2 < 2; k2++) {
      int sel = ((k2 << 2) | lquad) ^ sl;
      bf16x8 bv[4];
#pragma unroll
      for (int ni = 0; ni < 4; ni++) {
        int rowb = wn * 64 + ni * 16 + lrow;
        bv[ni] = *(const bf16x8*)((const char*)lds_b + rowb * 128 + sel * 16);
      }
#pragma unroll
      for (int mi = 0; mi < 4; mi++) {
        int rowa = wm * 64 + mi * 16 + lrow;
        bf16x8 av = *(const bf16x8*)((const char*)lds_a + rowa * 128 + sel * 16);
#pragma unroll
        for (int ni = 0; ni < 4; ni++)
          acc[mi][ni] =
              __builtin_amdgcn_mfma_f32_16x16x32_bf16(av, bv[ni], acc[mi][ni], 0, 0, 0);
      }
    }
    __syncthreads();
  }

  // ---- fused epilogue: exp, E store, ET store (LDS transpose), Z sums ----
  const int TS = 136;  // padded LDS row stride (u16) for 32x128 slice
  u16* T = lds_a;
  float colacc[4] = {0.f, 0.f, 0.f, 0.f};
#pragma unroll
  for (int s = 0; s < 4; s++) {
    if (wm == (s >> 1)) {
      int smi0 = (s & 1) * 2;
#pragma unroll
      for (int mi2 = 0; mi2 < 2; mi2++) {
        int mi = smi0 + mi2;
        float rowp[4] = {0.f, 0.f, 0.f, 0.f};
#pragma unroll
        for (int ni = 0; ni < 4; ni++) {
          int j = n0 + wn * 64 + ni * 16 + lrow;
          bool jv = j < 1600;
#pragma unroll
          for (int r = 0; r < 4; r++) {
            int i = m0 + wm * 64 + mi * 16 + lquad * 4 + r;
            float e = __expf(acc[mi][ni][r]);
            T[(mi2 * 16 + lquad * 4 + r) * TS + wn * 64 + ni * 16 + lrow] = f2bf(e);
            rowp[r] += jv ? e : 0.f;
            colacc[ni] += (i < 1600) ? e : 0.f;
          }
        }
#pragma unroll
        for (int r = 0; r < 4; r++) {
          float v = rowp[r];
          v += __shfl_xor(v, 1);
          v += __shfl_xor(v, 2);
          v += __shfl_xor(v, 4);
          v += __shfl_xor(v, 8);
          int i = m0 + wm * 64 + mi * 16 + lquad * 4 + r;
          if (lrow == 0 && i < 1600) atomicAdd(&Zrow[b * 1600 + i], v);
        }
      }
    }
    __syncthreads();
    // E rows: 32 rows x 128 cols, 16B coalesced stores
#pragma unroll
    for (int p = 0; p < 2; p++) {
      int jj = tid + p * 256;
      int ml = jj >> 4, n8 = jj & 15;
      int gi = m0 + s * 32 + ml, gj = n0 + n8 * 8;
      if (gi < 1600 && gj < 1600)
        *(uint4*)(Eb + (size_t)gi * 1600 + gj) = *(const uint4*)&T[ml * TS + n8 * 8];
    }
    // ET rows: transposed, 8B stores
#pragma unroll
    for (int p = 0; p < 4; p++) {
      int jj = tid + p * 256;
      int n = jj >> 3, m4 = jj & 7;
      int gm = m0 + s * 32 + m4 * 4, gn = n0 + n;
      if (gn < 1600 && gm < 1600) {
        ushort4 v;
        v.x = T[(m4 * 4 + 0) * TS + n];
        v.y = T[(m4 * 4 + 1) * TS + n];
        v.z = T[(m4 * 4 + 2) * TS + n];
        v.w = T[(m4 * 4 + 3) * TS + n];
        *(ushort4*)(ETb + (size_t)gn * 1600 + gm) = v;
      }
    }
    __syncthreads();
  }
#pragma unroll
  for (int ni = 0; ni < 4; ni++) {
    float v = colacc[ni];
    v += __shfl_xor(v, 16);
    v += __shfl_xor(v, 32);
    int j = n0 + wn * 64 + ni * 16 + lrow;
    if (lquad == 0 && j < 1600) atomicAdd(&Zcol[b * 1600 + j], v);
  }
}

// K3: out[idx] = bf16( x[idx] / Z[b][pixel] )   (both inputs via blockIdx.y)
__global__ void scale_div(const float* __restrict__ ex, const float* __restrict__ qu,
                          const float* __restrict__ Zcol, const float* __restrict__ Zrow,
                          u16* __restrict__ ebf, u16* __restrict__ qbf) {
  const float* x; const float* Z; u16* o;
  if (blockIdx.y == 0) { x = ex; Z = Zcol; o = ebf; }
  else { x = qu; Z = Zrow; o = qbf; }
  size_t idx = (size_t)blockIdx.x * 256 + threadIdx.x;  // 13,107,200
  int b = (int)(idx / 819200);
  int i = (int)(idx % 1600);
  o[idx] = f2bf(x[idx] / Z[b * 1600 + i]);
}

// ---------------------------------------------------------------------------
// K5: both 3x3 convs as 256x256-tile 8-phase counted-vmcnt GEMM (T2+T3+T4+T5).
// W: [512][4608] (k=t*512+c), ATT: padded [b][42*42][512] bf16. out fp32.
//
// LDS: per operand [dbuf 2][khalf 2][256 rows][32 elems] (64 KiB each, 128 KiB
// total). Each phase computes one (dbuf, k-slice, m-half) with 16 MFMA and
// restages the region that died at the previous phase's end barrier, 2 K-tiles
// ahead. vmcnt(6) only at phases 4/8 -> 3 half-tile stages stay in flight
// across barriers (no vmcnt(0) drain in the main loop).
// ---------------------------------------------------------------------------
__global__ __launch_bounds__(512, 2) void conv_gemm8p(
    const u16* __restrict__ W1, const u16* __restrict__ ATT1,
    const u16* __restrict__ W2, const u16* __restrict__ ATT2,
    float* __restrict__ out) {
  __shared__ u16 ldsA[32768];  // [2][2][256][32]
  __shared__ u16 ldsB[32768];
  int tid = threadIdx.x;
  int z = blockIdx.z, b = z & 15, sel2 = z >> 4;
  const u16* W = sel2 ? W2 : W1;
  const u16* attb = (sel2 ? ATT2 : ATT1) + (size_t)b * 903168;
  float* outb = out + (size_t)b * 1638400 + (size_t)(sel2 ? 512 : 0) * 1600;
  int p0 = blockIdx.x * 256, o0 = blockIdx.y * 256;

  // ---- staging setup (source pre-swizzle, linear LDS dest) ----
  int rl = tid >> 2;                      // local row 0..127 (j adds 128)
  int cs = (tid & 3) ^ ((rl >> 1) & 3);   // swizzled 16B source chunk (of 4)
  const char* pA0 = (const char*)(W + (size_t)(o0 + rl) * 4608) + cs * 16;
  const char* pA1 = pA0 + 128 * 9216;
  int pp0 = p0 + rl; pp0 = pp0 < 1600 ? pp0 : 1599;
  int y0 = pp0 / 40, x0 = pp0 - y0 * 40;
  const char* pB0 = (const char*)(attb + (size_t)(y0 * 42 + x0) * 512) + cs * 16;
  int pp1 = p0 + 128 + rl; pp1 = pp1 < 1600 ? pp1 : 1599;
  int y1 = pp1 / 40, x1 = pp1 - y1 * 40;
  const char* pB1 = (const char*)(attb + (size_t)(y1 * 42 + x1) * 512) + cs * 16;

  char* ldsAb = (char*)ldsA;
  char* ldsBb = (char*)ldsB;
  int dstT = tid * 16;

#define STAGE_A(d, kh, kt)                                              \
  {                                                                     \
    int ko = (kt) * 128 + (kh) * 64;                                    \
    gll16(pA0 + ko, ldsAb + ((d) * 2 + (kh)) * 16384 + dstT);           \
    gll16(pA1 + ko, ldsAb + ((d) * 2 + (kh)) * 16384 + 8192 + dstT);    \
  }
#define STAGE_B(d, kh, kt)                                              \
  {                                                                     \
    int tp = (kt) >> 3;                                                 \
    int ty = (tp * 11) >> 5;                                            \
    int tx = tp - ty * 3;                                               \
    int ko = (ty * 42 + tx) * 1024 + ((kt) & 7) * 128 + (kh) * 64;      \
    gll16(pB0 + ko, ldsBb + ((d) * 2 + (kh)) * 16384 + dstT);           \
    gll16(pB1 + ko, ldsBb + ((d) * 2 + (kh)) * 16384 + 8192 + dstT);    \
  }

  // ---- compute-side lane mapping ----
  int wid = tid >> 6, lane = tid & 63;
  int wm = wid & 1, wn = wid >> 1;             // 2 M-warps x 4 N-warps
  int lrow = lane & 15, lquad = lane >> 4;
  int csel = (lquad ^ ((lrow >> 1) & 3)) << 4;
  int aBase = (wm * 128 + lrow) * 64 + csel;   // byte offset within region
  int bBase = (wn * 64 + lrow) * 64 + csel;

  const f32x4 fzero = {0.f, 0.f, 0.f, 0.f};
  f32x4 acc[8][4];
#pragma unroll
  for (int mi = 0; mi < 8; mi++)
#pragma unroll
    for (int ni = 0; ni < 4; ni++) acc[mi][ni] = fzero;

  // ---- prologue: dbuf0 <- kt0, dbuf1 <- kt1 (3 of 4 regions) ----
  STAGE_B(0, 0, 0); STAGE_A(0, 0, 0); STAGE_B(0, 1, 0); STAGE_A(0, 1, 0);
  STAGE_B(1, 0, 1); STAGE_A(1, 0, 1); STAGE_B(1, 1, 1);
  asm volatile("s_waitcnt vmcnt(6)" ::: "memory");  // dbuf0 fully landed
  __builtin_amdgcn_s_barrier();

  bf16x8 bv0, bv1, bv2, bv3;

#define MFMA4(mi, av)                                                          \
  acc[mi][0] = __builtin_amdgcn_mfma_f32_16x16x32_bf16(av, bv0, acc[mi][0], 0, 0, 0); \
  acc[mi][1] = __builtin_amdgcn_mfma_f32_16x16x32_bf16(av, bv1, acc[mi][1], 0, 0, 0); \
  acc[mi][2] = __builtin_amdgcn_mfma_f32_16x16x32_bf16(av, bv2, acc[mi][2], 0, 0, 0); \
  acc[mi][3] = __builtin_amdgcn_mfma_f32_16x16x32_bf16(av, bv3, acc[mi][3], 0, 0, 0);

#define PHASE(d, kh, mh, STG, VM)                                              \
  {                                                                            \
    const char* ra_ = ldsAb + ((d) * 2 + (kh)) * 16384 + aBase + (mh) * 4096;  \
    bf16x8 av0 = *(const bf16x8*)(ra_);                                        \
    bf16x8 av1 = *(const bf16x8*)(ra_ + 1024);                                 \
    bf16x8 av2 = *(const bf16x8*)(ra_ + 2048);                                 \
    bf16x8 av3 = *(const bf16x8*)(ra_ + 3072);                                 \
    if ((mh) == 0) {                                                           \
      const char* rb_ = ldsBb + ((d) * 2 + (kh)) * 16384 + bBase;              \
      bv0 = *(const bf16x8*)(rb_);                                             \
      bv1 = *(const bf16x8*)(rb_ + 1024);                                      \
      bv2 = *(const bf16x8*)(rb_ + 2048);                                      \
      bv3 = *(const bf16x8*)(rb_ + 3072);                                      \
    }                                                                          \
    STG;                                                                       \
    VM;                                                                        \
    __builtin_amdgcn_s_barrier();                                              \
    asm volatile("s_waitcnt lgkmcnt(0)" ::: "memory");                         \
    __builtin_amdgcn_sched_barrier(0);                                         \
    __builtin_amdgcn_s_setprio(1);                                             \
    MFMA4((mh) * 4 + 0, av0);                                                  \
    MFMA4((mh) * 4 + 1, av1);                                                  \
    MFMA4((mh) * 4 + 2, av2);                                                  \
    MFMA4((mh) * 4 + 3, av3);                                                  \
    __builtin_amdgcn_s_setprio(0);                                             \
    __builtin_amdgcn_sched_barrier(0);                                         \
    __builtin_amdgcn_s_barrier();                                              \
  }

#define VMW asm volatile("s_waitcnt vmcnt(6)" ::: "memory")

#pragma unroll 1
  for (int it = 0; it < 36; ++it) {
    int ktb = it * 2;
    int kt1 = ktb + 1;
    int kt2 = ktb + 2 < 72 ? ktb + 2 : 71;  // clamped (redundant on last iters)
    int kt3 = ktb + 3 < 72 ? ktb + 3 : 71;
    PHASE(0, 0, 0, STAGE_A(1, 1, kt1), (void)0);
    PHASE(0, 0, 1, STAGE_B(0, 0, kt2), (void)0);
    PHASE(0, 1, 0, STAGE_A(0, 0, kt2), (void)0);
    PHASE(0, 1, 1, STAGE_B(0, 1, kt2), VMW);
    PHASE(1, 0, 0, STAGE_A(0, 1, kt2), (void)0);
    PHASE(1, 0, 1, STAGE_B(1, 0, kt3), (void)0);
    PHASE(1, 1, 0, STAGE_A(1, 0, kt3), (void)0);
    PHASE(1, 1, 1, STAGE_B(1, 1, kt3), VMW);
  }

#undef PHASE
#undef MFMA4
#undef VMW
#undef STAGE_A
#undef STAGE_B

  // ---- epilogue: fp32 stores, guard pixel tail ----
#pragma unroll
  for (int mi = 0; mi < 8; mi++) {
#pragma unroll
    for (int r = 0; r < 4; r++) {
      int o = o0 + wm * 128 + mi * 16 + lquad * 4 + r;
      float* orow = outb + (size_t)o * 1600;
#pragma unroll
      for (int ni = 0; ni < 4; ni++) {
        int p = p0 + wn * 64 + ni * 16 + lrow;
        if (p < 1600) orow[p] = acc[mi][ni][r];
      }
    }
  }
}

// ---------------------------------------------------------------------------
extern "C" void kernel_launch(void* const* d_in, const int* in_sizes, int n_in,
                              void* d_out, int out_size, void* d_ws, size_t ws_size,
                              hipStream_t stream) {
  const float* ex = (const float*)d_in[0];
  const float* qu = (const float*)d_in[1];
  const float* w_e = (const float*)d_in[2];
  const float* w_q = (const float*)d_in[3];
  const float* w_c1 = (const float*)d_in[4];
  const float* w_c2 = (const float*)d_in[5];
  float* out = (float*)d_out;
  char* ws = (char*)d_ws;

  u16* E     = (u16*)(ws + 0L);            // 81,920,000
  u16* ET    = (u16*)(ws + 81920000L);     // 81,920,000
  u16* xt_e  = (u16*)(ws + 163840000L);    // 26,214,400 (reused as ebf)
  u16* xt_q  = (u16*)(ws + 190054400L);    // 26,214,400 (reused as qbf)
  u16* ecorr = (u16*)(ws + 216268800L);    // 13,107,200
  u16* qcorr = (u16*)(ws + 229376000L);    // 13,107,200
  u16* att_e = (u16*)(ws + 242483200L);    // 28,901,376
  u16* att_q = (u16*)(ws + 271384576L);    // 28,901,376
  float* Zrow = (float*)(ws + 300285952L); // 102,400
  float* Zcol = (float*)(ws + 300388352L); // 102,400
  u16* w_ebf = (u16*)(ws + 300490752L);    // 262,144
  u16* w_qbf = (u16*)(ws + 300752896L);    // 262,144
  u16* wr1   = (u16*)(ws + 301015040L);    // 4,718,592
  u16* wr2   = (u16*)(ws + 305733632L);    // 4,718,592  (total 310,452,224)

  // prep
  transp_cast_x2<<<dim3(50, 16, 32), 256, 0, stream>>>(ex, qu, xt_e, xt_q);
  cast_w<<<dim3(512), 256, 0, stream>>>(w_e, w_q, w_ebf, w_qbf);
  repack_wc<<<dim3(9216, 2), 256, 0, stream>>>(w_c1, w_c2, wr1, wr2);
  // zero att_e, att_q, Zrow, Zcol (contiguous): 58,007,552 B
  zero_mem<<<dim3(2048), 256, 0, stream>>>((uint4*)att_e, 3625472L);

  // K1: corr[b][n][o] = sum_c xt[n,c] * w[o,c]   (both e and q in one grid)
  gemm_bt64<0><<<dim3(13, 2, 32), 256, 0, stream>>>(
      xt_e, w_ebf, ecorr, xt_q, w_qbf, qcorr, 1600, 256, 512, 819200L, 0L, 409600L);

  // K2: E/ET/Zrow/Zcol fused
  gemm_corr_exp<<<dim3(13, 13, 16), 256, 0, stream>>>(ecorr, qcorr, E, ET, Zrow, Zcol);

  // K3: scale inputs by softmax denominators
  u16* ebf = xt_e;
  u16* qbf = xt_q;
  scale_div<<<dim3(51200, 2), 256, 0, stream>>>(ex, qu, Zcol, Zrow, ebf, qbf);

  // K4: att_q[p][c] = sum_i E[p,i]*ebf[c,i] ; att_e[p][c] = sum_i ET[p,i]*qbf[c,i]
  gemm_bt64<2><<<dim3(13, 4, 32), 256, 0, stream>>>(
      E, ebf, att_q, ET, qbf, att_e, 1600, 512, 1600, 2560000L, 819200L, 903168L);

  // K5: both convs, 256x256 8-phase; ch 0..511 = conv(att_e, w_c1), 512.. = conv(att_q, w_c2)
  conv_gemm8p<<<dim3(7, 2, 32), 512, 0, stream>>>(wr1, att_e, wr2, att_q, out);
}

// Round 2
// 838.042 us; speedup vs baseline: 1.1103x; 1.0345x over previous
//
#include <hip/hip_runtime.h>

typedef unsigned short u16;
typedef __attribute__((ext_vector_type(8))) short bf16x8;
typedef __attribute__((ext_vector_type(4))) float f32x4;

__device__ __forceinline__ u16 f2bf(float f) {
  union { float f; unsigned u; } v; v.f = f;
  unsigned u = v.u;
  u += 0x7fffu + ((u >> 16) & 1u);
  return (u16)(u >> 16);
}

__device__ __forceinline__ void gll16(const void* g, void* l) {
  __builtin_amdgcn_global_load_lds(
      (const __attribute__((address_space(1))) void*)g,
      (__attribute__((address_space(3))) void*)l, 16, 0, 0);
}

// ---------------------------------------------------------------------------
// P1: x[b][c][n] f32 -> xt[b][n][c] bf16   (C=512, N=1600), both inputs
// ---------------------------------------------------------------------------
__global__ __launch_bounds__(256) void transp_cast_x2(const float* __restrict__ ex,
                                                      const float* __restrict__ qu,
                                                      u16* __restrict__ xte,
                                                      u16* __restrict__ xtq) {
  __shared__ float t[32][33];
  int z = blockIdx.z;
  int b = z & 15;
  const float* xb = (z < 16 ? ex : qu) + (size_t)b * 819200;
  u16* xtb = (z < 16 ? xte : xtq) + (size_t)b * 819200;
  int n0 = blockIdx.x * 32, c0 = blockIdx.y * 32;
  int tx = threadIdx.x & 31, ty = threadIdx.x >> 5;
#pragma unroll
  for (int k = 0; k < 4; k++) {
    int c = ty + k * 8;
    t[c][tx] = xb[(size_t)(c0 + c) * 1600 + n0 + tx];
  }
  __syncthreads();
#pragma unroll
  for (int k = 0; k < 4; k++) {
    int n = ty + k * 8;
    xtb[(size_t)(n0 + n) * 512 + c0 + tx] = f2bf(t[tx][n]);
  }
}

// P2: cast w_e / w_q (256x512 each) to bf16
__global__ void cast_w(const float* __restrict__ we, const float* __restrict__ wq,
                       u16* __restrict__ oe, u16* __restrict__ oq) {
  int i = blockIdx.x * 256 + threadIdx.x;
  oe[i] = f2bf(we[i]);
  oq[i] = f2bf(wq[i]);
}

// P3: w[o][c][ky][kx] f32 -> wr[o][t*512+c] bf16 (both conv weights)
__global__ void repack_wc(const float* __restrict__ w1, const float* __restrict__ w2,
                          u16* __restrict__ o1, u16* __restrict__ o2) {
  const float* w = blockIdx.y ? w2 : w1;
  u16* wr = blockIdx.y ? o2 : o1;
  int idx = blockIdx.x * 256 + threadIdx.x;  // 2359296 total
  int o = idx / 4608;
  int r = idx - o * 4608;
  int t = r >> 9;
  int c = r & 511;
  wr[idx] = f2bf(w[o * 4608 + c * 9 + t]);
}

// P4: zero att buffers + Z buffers
__global__ void zero_mem(uint4* __restrict__ p, long n) {
  long i = (long)blockIdx.x * blockDim.x + threadIdx.x;
  long stride = (long)gridDim.x * blockDim.x;
  uint4 z; z.x = 0; z.y = 0; z.z = 0; z.w = 0;
  for (; i < n; i += stride) p[i] = z;
}

// ---------------------------------------------------------------------------
// Generic A*B^T bf16 GEMM, 128x128 tile, BK=64, XOR-swizzled LDS,
// dual problem sets selected by blockIdx.z (z<16 -> set1, else set2).
// MODE 0: store bf16 C[i*N+j].  MODE 2: store bf16 to padded pixel layout.
// ---------------------------------------------------------------------------
template <int MODE>
__global__ __launch_bounds__(256) void gemm_bt64(
    const u16* __restrict__ A, const u16* __restrict__ B, u16* __restrict__ C,
    const u16* __restrict__ A2, const u16* __restrict__ B2, u16* __restrict__ C2,
    int M, int N, int K, long sA, long sB, long sC) {
  __shared__ u16 lds_a[128 * 64];
  __shared__ u16 lds_b[128 * 64];
  int tid = threadIdx.x;
  int z = blockIdx.z, b = z & 15;
  const u16* Ab = (z < 16 ? A : A2) + (size_t)b * sA;
  const u16* Bb = (z < 16 ? B : B2) + (size_t)b * sB;
  u16* Cb = (z < 16 ? C : C2) + (size_t)b * sC;
  int m0 = blockIdx.x * 128, n0 = blockIdx.y * 128;

  int rsub = tid >> 3;                     // 0..31
  int gch = (tid & 7) ^ (rsub & 7);        // swizzled 16B chunk to fetch
  long Kb = (long)K * 2;
  const char* pa[4];
  const char* pb[4];
#pragma unroll
  for (int c = 0; c < 4; c++) {
    int ra = m0 + 32 * c + rsub; ra = ra < M ? ra : M - 1;
    int rb = n0 + 32 * c + rsub; rb = rb < N ? rb : N - 1;
    pa[c] = (const char*)Ab + (long)ra * Kb + gch * 16;
    pb[c] = (const char*)Bb + (long)rb * Kb + gch * 16;
  }

  const f32x4 fzero = {0.f, 0.f, 0.f, 0.f};
  f32x4 acc[4][4];
#pragma unroll
  for (int mi = 0; mi < 4; mi++)
#pragma unroll
    for (int ni = 0; ni < 4; ni++) acc[mi][ni] = fzero;

  int wid = tid >> 6, lane = tid & 63;
  int wm = wid & 1, wn = wid >> 1;
  int lrow = lane & 15, lquad = lane >> 4;
  int sl = lrow & 7;

  int ksteps = K >> 6;
  for (int ks = 0; ks < ksteps; ks++) {
#pragma unroll
    for (int c = 0; c < 4; c++) {
      gll16(pa[c], (char*)lds_a + c * 4096 + tid * 16);
      gll16(pb[c], (char*)lds_b + c * 4096 + tid * 16);
      pa[c] += 128; pb[c] += 128;
    }
    __syncthreads();
#pragma unroll
    for (int k2 = 0; k2 < 2; k2++) {
      int sel = ((k2 << 2) | lquad) ^ sl;
      bf16x8 bv[4];
#pragma unroll
      for (int ni = 0; ni < 4; ni++) {
        int rowb = wn * 64 + ni * 16 + lrow;
        bv[ni] = *(const bf16x8*)((const char*)lds_b + rowb * 128 + sel * 16);
      }
#pragma unroll
      for (int mi = 0; mi < 4; mi++) {
        int rowa = wm * 64 + mi * 16 + lrow;
        bf16x8 av = *(const bf16x8*)((const char*)lds_a + rowa * 128 + sel * 16);
#pragma unroll
        for (int ni = 0; ni < 4; ni++)
          acc[mi][ni] =
              __builtin_amdgcn_mfma_f32_16x16x32_bf16(av, bv[ni], acc[mi][ni], 0, 0, 0);
      }
    }
    __syncthreads();
  }

#pragma unroll
  for (int mi = 0; mi < 4; mi++) {
#pragma unroll
    for (int r = 0; r < 4; r++) {
      int i = m0 + wm * 64 + mi * 16 + lquad * 4 + r;
      if (i >= M) continue;
#pragma unroll
      for (int ni = 0; ni < 4; ni++) {
        int j = n0 + wn * 64 + ni * 16 + lrow;
        if (j >= N) continue;
        float v = acc[mi][ni][r];
        if (MODE == 2) {
          int y = i / 40, x = i - y * 40;
          Cb[(size_t)((y + 1) * 42 + (x + 1)) * 512 + j] = f2bf(v);
        } else {
          Cb[(size_t)i * N + j] = f2bf(v);
        }
      }
    }
  }
}

// ---------------------------------------------------------------------------
// K2: E = exp(ecorr * qcorr^T)  [1600x1600 per batch, K=256]
// Fused epilogue: E (coalesced 16B rows), ET (LDS transpose), Zrow/Zcol sums
// via shuffle + atomics.
// ---------------------------------------------------------------------------
__global__ __launch_bounds__(256) void gemm_corr_exp(
    const u16* __restrict__ A, const u16* __restrict__ B, u16* __restrict__ E,
    u16* __restrict__ ET, float* __restrict__ Zrow, float* __restrict__ Zcol) {
  __shared__ u16 lds_a[128 * 64];
  __shared__ u16 lds_b[128 * 64];
  int tid = threadIdx.x;
  int b = blockIdx.z;
  const u16* Ab = A + (size_t)b * 409600;
  const u16* Bb = B + (size_t)b * 409600;
  u16* Eb = E + (size_t)b * 2560000;
  u16* ETb = ET + (size_t)b * 2560000;
  int m0 = blockIdx.x * 128, n0 = blockIdx.y * 128;

  int rsub = tid >> 3;
  int gch = (tid & 7) ^ (rsub & 7);
  const char* pa[4];
  const char* pb[4];
#pragma unroll
  for (int c = 0; c < 4; c++) {
    int ra = m0 + 32 * c + rsub; ra = ra < 1600 ? ra : 1599;
    int rb = n0 + 32 * c + rsub; rb = rb < 1600 ? rb : 1599;
    pa[c] = (const char*)(Ab + (size_t)ra * 256) + gch * 16;
    pb[c] = (const char*)(Bb + (size_t)rb * 256) + gch * 16;
  }

  const f32x4 fzero = {0.f, 0.f, 0.f, 0.f};
  f32x4 acc[4][4];
#pragma unroll
  for (int mi = 0; mi < 4; mi++)
#pragma unroll
    for (int ni = 0; ni < 4; ni++) acc[mi][ni] = fzero;

  int wid = tid >> 6, lane = tid & 63;
  int wm = wid & 1, wn = wid >> 1;
  int lrow = lane & 15, lquad = lane >> 4;
  int sl = lrow & 7;

  for (int ks = 0; ks < 4; ks++) {
#pragma unroll
    for (int c = 0; c < 4; c++) {
      gll16(pa[c], (char*)lds_a + c * 4096 + tid * 16);
      gll16(pb[c], (char*)lds_b + c * 4096 + tid * 16);
      pa[c] += 128; pb[c] += 128;
    }
    __syncthreads();
#pragma unroll
    for (int k2 = 0; k2 < 2; k2++) {
      int sel = ((k2 << 2) | lquad) ^ sl;
      bf16x8 bv[4];
#pragma unroll
      for (int ni = 0; ni < 4; ni++) {
        int rowb = wn * 64 + ni * 16 + lrow;
        bv[ni] = *(const bf16x8*)((const char*)lds_b + rowb * 128 + sel * 16);
      }
#pragma unroll
      for (int mi = 0; mi < 4; mi++) {
        int rowa = wm * 64 + mi * 16 + lrow;
        bf16x8 av = *(const bf16x8*)((const char*)lds_a + rowa * 128 + sel * 16);
#pragma unroll
        for (int ni = 0; ni < 4; ni++)
          acc[mi][ni] =
              __builtin_amdgcn_mfma_f32_16x16x32_bf16(av, bv[ni], acc[mi][ni], 0, 0, 0);
      }
    }
    __syncthreads();
  }

  // ---- fused epilogue: exp, E store, ET store (LDS transpose), Z sums ----
  const int TS = 136;  // padded LDS row stride (u16) for 32x128 slice
  u16* T = lds_a;
  float colacc[4] = {0.f, 0.f, 0.f, 0.f};
#pragma unroll
  for (int s = 0; s < 4; s++) {
    if (wm == (s >> 1)) {
      int smi0 = (s & 1) * 2;
#pragma unroll
      for (int mi2 = 0; mi2 < 2; mi2++) {
        int mi = smi0 + mi2;
        float rowp[4] = {0.f, 0.f, 0.f, 0.f};
#pragma unroll
        for (int ni = 0; ni < 4; ni++) {
          int j = n0 + wn * 64 + ni * 16 + lrow;
          bool jv = j < 1600;
#pragma unroll
          for (int r = 0; r < 4; r++) {
            int i = m0 + wm * 64 + mi * 16 + lquad * 4 + r;
            float e = __expf(acc[mi][ni][r]);
            T[(mi2 * 16 + lquad * 4 + r) * TS + wn * 64 + ni * 16 + lrow] = f2bf(e);
            rowp[r] += jv ? e : 0.f;
            colacc[ni] += (i < 1600) ? e : 0.f;
          }
        }
#pragma unroll
        for (int r = 0; r < 4; r++) {
          float v = rowp[r];
          v += __shfl_xor(v, 1);
          v += __shfl_xor(v, 2);
          v += __shfl_xor(v, 4);
          v += __shfl_xor(v, 8);
          int i = m0 + wm * 64 + mi * 16 + lquad * 4 + r;
          if (lrow == 0 && i < 1600) atomicAdd(&Zrow[b * 1600 + i], v);
        }
      }
    }
    __syncthreads();
    // E rows: 32 rows x 128 cols, 16B coalesced stores
#pragma unroll
    for (int p = 0; p < 2; p++) {
      int jj = tid + p * 256;
      int ml = jj >> 4, n8 = jj & 15;
      int gi = m0 + s * 32 + ml, gj = n0 + n8 * 8;
      if (gi < 1600 && gj < 1600)
        *(uint4*)(Eb + (size_t)gi * 1600 + gj) = *(const uint4*)&T[ml * TS + n8 * 8];
    }
    // ET rows: transposed, 8B stores
#pragma unroll
    for (int p = 0; p < 4; p++) {
      int jj = tid + p * 256;
      int n = jj >> 3, m4 = jj & 7;
      int gm = m0 + s * 32 + m4 * 4, gn = n0 + n;
      if (gn < 1600 && gm < 1600) {
        ushort4 v;
        v.x = T[(m4 * 4 + 0) * TS + n];
        v.y = T[(m4 * 4 + 1) * TS + n];
        v.z = T[(m4 * 4 + 2) * TS + n];
        v.w = T[(m4 * 4 + 3) * TS + n];
        *(ushort4*)(ETb + (size_t)gn * 1600 + gm) = v;
      }
    }
    __syncthreads();
  }
#pragma unroll
  for (int ni = 0; ni < 4; ni++) {
    float v = colacc[ni];
    v += __shfl_xor(v, 16);
    v += __shfl_xor(v, 32);
    int j = n0 + wn * 64 + ni * 16 + lrow;
    if (lquad == 0 && j < 1600) atomicAdd(&Zcol[b * 1600 + j], v);
  }
}

// K3: out[idx] = bf16( x[idx] / Z[b][pixel] )   (both inputs via blockIdx.y)
__global__ void scale_div(const float* __restrict__ ex, const float* __restrict__ qu,
                          const float* __restrict__ Zcol, const float* __restrict__ Zrow,
                          u16* __restrict__ ebf, u16* __restrict__ qbf) {
  const float* x; const float* Z; u16* o;
  if (blockIdx.y == 0) { x = ex; Z = Zcol; o = ebf; }
  else { x = qu; Z = Zrow; o = qbf; }
  size_t idx = (size_t)blockIdx.x * 256 + threadIdx.x;  // 13,107,200
  int b = (int)(idx / 819200);
  int i = (int)(idx % 1600);
  o[idx] = f2bf(x[idx] / Z[b * 1600 + i]);
}

// ---------------------------------------------------------------------------
// K5: both 3x3 convs as 256(o)x224(p)-tile 4-phase counted-vmcnt GEMM.
// W: [512][4608] (k=t*512+c), ATT: padded [b][42*42][512] bf16. out fp32.
//
// Grid: 8 p-tiles x 2 o-tiles x 32 z = 512 blocks = exactly 2 full CU rounds
// (tail idle eliminated). 8 waves as 4(o) x 2(p); wave tile 64x112,
// acc[4][7]. Per phase: 11 ds_read_b128 + 1 region restage (4 gll16) +
// vmcnt(8) + barrier + 28 MFMA + barrier. B staged padded to 256 rows so all
// waves issue identical vm-op counts. LDS 128 KiB (1 block/CU).
// ---------------------------------------------------------------------------
__global__ __launch_bounds__(512, 2) void conv_gemm4p(
    const u16* __restrict__ W1, const u16* __restrict__ ATT1,
    const u16* __restrict__ W2, const u16* __restrict__ ATT2,
    float* __restrict__ out) {
  __shared__ u16 ldsA[32768];  // [2][2][256 rows][32 elems]
  __shared__ u16 ldsB[32768];  // [2][2][256 rows][32 elems] (rows 224+ dummy)
  int tid = threadIdx.x;
  int z = blockIdx.z, b = z & 15, sel2 = z >> 4;
  const u16* W = sel2 ? W2 : W1;
  const u16* attb = (sel2 ? ATT2 : ATT1) + (size_t)b * 903168;
  float* outb = out + (size_t)b * 1638400 + (size_t)(sel2 ? 512 : 0) * 1600;
  int p0 = blockIdx.x * 224, o0 = blockIdx.y * 256;

  // ---- staging setup (source pre-swizzle, linear LDS dest) ----
  int rl = tid >> 2;                      // local row 0..127 (second call +128)
  int cs = (tid & 3) ^ ((rl >> 1) & 3);   // swizzled 16B source chunk (of 4)
  const char* pA0 = (const char*)(W + (size_t)(o0 + rl) * 4608) + cs * 16;
  const char* pA1 = pA0 + 128 * 9216;
  int pp0 = p0 + rl; pp0 = pp0 < 1600 ? pp0 : 1599;
  int y0 = pp0 / 40, x0 = pp0 - y0 * 40;
  const char* pB0 = (const char*)(attb + (size_t)(y0 * 42 + x0) * 512) + cs * 16;
  int pp1 = p0 + 128 + rl; pp1 = pp1 < 1600 ? pp1 : 1599;  // rows 224+ dummy
  int y1 = pp1 / 40, x1 = pp1 - y1 * 40;
  const char* pB1 = (const char*)(attb + (size_t)(y1 * 42 + x1) * 512) + cs * 16;

  char* ldsAb = (char*)ldsA;
  char* ldsBb = (char*)ldsB;
  int dstT = tid * 16;

#define STAGE_A(d, kh, kt)                                              \
  {                                                                     \
    int ko = (kt) * 128 + (kh) * 64;                                    \
    gll16(pA0 + ko, ldsAb + ((d) * 2 + (kh)) * 16384 + dstT);           \
    gll16(pA1 + ko, ldsAb + ((d) * 2 + (kh)) * 16384 + 8192 + dstT);    \
  }
#define STAGE_B(d, kh, kt)                                              \
  {                                                                     \
    int tp = (kt) >> 3;                                                 \
    int ty = (tp * 11) >> 5;                                            \
    int tx = tp - ty * 3;                                               \
    int ko = (ty * 42 + tx) * 1024 + ((kt) & 7) * 128 + (kh) * 64;      \
    gll16(pB0 + ko, ldsBb + ((d) * 2 + (kh)) * 16384 + dstT);           \
    gll16(pB1 + ko, ldsBb + ((d) * 2 + (kh)) * 16384 + 8192 + dstT);    \
  }
#define STAGE_U(d, kh, kt) { STAGE_A(d, kh, kt); STAGE_B(d, kh, kt); }

  // ---- compute-side lane mapping ----
  int wid = tid >> 6, lane = tid & 63;
  int wm = wid & 3, wn = wid >> 2;             // 4 o-waves x 2 p-waves
  int lrow = lane & 15, lquad = lane >> 4;
  int csel = (lquad ^ ((lrow >> 1) & 3)) << 4;
  int aBase = (wm * 64 + lrow) * 64 + csel;    // byte offset within region
  int bBase = (wn * 112 + lrow) * 64 + csel;

  const f32x4 fzero = {0.f, 0.f, 0.f, 0.f};
  f32x4 acc[4][7];
#pragma unroll
  for (int mi = 0; mi < 4; mi++)
#pragma unroll
    for (int ni = 0; ni < 7; ni++) acc[mi][ni] = fzero;

  // ---- prologue: (0,k0),(0,k1) <- kt0 ; (1,k0) <- kt1 ----
  STAGE_U(0, 0, 0);
  STAGE_U(0, 1, 0);
  STAGE_U(1, 0, 1);
  asm volatile("s_waitcnt vmcnt(8)" ::: "memory");  // (0,k0) landed
  __builtin_amdgcn_s_barrier();

#define MROW(mi, av)                                                                   \
  acc[mi][0] = __builtin_amdgcn_mfma_f32_16x16x32_bf16(av, bv0, acc[mi][0], 0, 0, 0);  \
  acc[mi][1] = __builtin_amdgcn_mfma_f32_16x16x32_bf16(av, bv1, acc[mi][1], 0, 0, 0);  \
  acc[mi][2] = __builtin_amdgcn_mfma_f32_16x16x32_bf16(av, bv2, acc[mi][2], 0, 0, 0);  \
  acc[mi][3] = __builtin_amdgcn_mfma_f32_16x16x32_bf16(av, bv3, acc[mi][3], 0, 0, 0);  \
  acc[mi][4] = __builtin_amdgcn_mfma_f32_16x16x32_bf16(av, bv4, acc[mi][4], 0, 0, 0);  \
  acc[mi][5] = __builtin_amdgcn_mfma_f32_16x16x32_bf16(av, bv5, acc[mi][5], 0, 0, 0);  \
  acc[mi][6] = __builtin_amdgcn_mfma_f32_16x16x32_bf16(av, bv6, acc[mi][6], 0, 0, 0);

#define PHASE(d, kh, STG)                                                      \
  {                                                                            \
    const char* ra_ = ldsAb + ((d) * 2 + (kh)) * 16384 + aBase;                \
    const char* rb_ = ldsBb + ((d) * 2 + (kh)) * 16384 + bBase;                \
    bf16x8 av0 = *(const bf16x8*)(ra_);                                        \
    bf16x8 av1 = *(const bf16x8*)(ra_ + 1024);                                 \
    bf16x8 av2 = *(const bf16x8*)(ra_ + 2048);                                 \
    bf16x8 av3 = *(const bf16x8*)(ra_ + 3072);                                 \
    bf16x8 bv0 = *(const bf16x8*)(rb_);                                        \
    bf16x8 bv1 = *(const bf16x8*)(rb_ + 1024);                                 \
    bf16x8 bv2 = *(const bf16x8*)(rb_ + 2048);                                 \
    bf16x8 bv3 = *(const bf16x8*)(rb_ + 3072);                                 \
    bf16x8 bv4 = *(const bf16x8*)(rb_ + 4096);                                 \
    bf16x8 bv5 = *(const bf16x8*)(rb_ + 5120);                                 \
    bf16x8 bv6 = *(const bf16x8*)(rb_ + 6144);                                 \
    STG;                                                                       \
    asm volatile("s_waitcnt vmcnt(8)" ::: "memory");                           \
    __builtin_amdgcn_s_barrier();                                              \
    asm volatile("s_waitcnt lgkmcnt(0)" ::: "memory");                         \
    __builtin_amdgcn_sched_barrier(0);                                         \
    __builtin_amdgcn_s_setprio(1);                                             \
    MROW(0, av0)                                                               \
    MROW(1, av1)                                                               \
    MROW(2, av2)                                                               \
    MROW(3, av3)                                                               \
    __builtin_amdgcn_s_setprio(0);                                             \
    __builtin_amdgcn_sched_barrier(0);                                         \
    __builtin_amdgcn_s_barrier();                                              \
  }

#pragma unroll 1
  for (int it = 0; it < 36; ++it) {
    int ktb = it * 2;
    int kt1 = ktb + 1;
    int kt2 = ktb + 2 < 72 ? ktb + 2 : 71;  // clamped (garbage on last iter, unread)
    int kt3 = ktb + 3 < 72 ? ktb + 3 : 71;
    PHASE(0, 0, STAGE_U(1, 1, kt1));  // just-in-time: read at PH4
    PHASE(0, 1, STAGE_U(0, 0, kt2));
    PHASE(1, 0, STAGE_U(0, 1, kt2));
    PHASE(1, 1, STAGE_U(1, 0, kt3));
  }

#undef PHASE
#undef MROW
#undef STAGE_U
#undef STAGE_A
#undef STAGE_B

  // ---- epilogue: fp32 stores, guard pixel tail ----
#pragma unroll
  for (int mi = 0; mi < 4; mi++) {
#pragma unroll
    for (int r = 0; r < 4; r++) {
      int o = o0 + wm * 64 + mi * 16 + lquad * 4 + r;
      float* orow = outb + (size_t)o * 1600;
#pragma unroll
      for (int ni = 0; ni < 7; ni++) {
        int p = p0 + wn * 112 + ni * 16 + lrow;
        if (p < 1600) orow[p] = acc[mi][ni][r];
      }
    }
  }
}

// ---------------------------------------------------------------------------
extern "C" void kernel_launch(void* const* d_in, const int* in_sizes, int n_in,
                              void* d_out, int out_size, void* d_ws, size_t ws_size,
                              hipStream_t stream) {
  const float* ex = (const float*)d_in[0];
  const float* qu = (const float*)d_in[1];
  const float* w_e = (const float*)d_in[2];
  const float* w_q = (const float*)d_in[3];
  const float* w_c1 = (const float*)d_in[4];
  const float* w_c2 = (const float*)d_in[5];
  float* out = (float*)d_out;
  char* ws = (char*)d_ws;

  u16* E     = (u16*)(ws + 0L);            // 81,920,000
  u16* ET    = (u16*)(ws + 81920000L);     // 81,920,000
  u16* xt_e  = (u16*)(ws + 163840000L);    // 26,214,400 (reused as ebf)
  u16* xt_q  = (u16*)(ws + 190054400L);    // 26,214,400 (reused as qbf)
  u16* ecorr = (u16*)(ws + 216268800L);    // 13,107,200
  u16* qcorr = (u16*)(ws + 229376000L);    // 13,107,200
  u16* att_e = (u16*)(ws + 242483200L);    // 28,901,376
  u16* att_q = (u16*)(ws + 271384576L);    // 28,901,376
  float* Zrow = (float*)(ws + 300285952L); // 102,400
  float* Zcol = (float*)(ws + 300388352L); // 102,400
  u16* w_ebf = (u16*)(ws + 300490752L);    // 262,144
  u16* w_qbf = (u16*)(ws + 300752896L);    // 262,144
  u16* wr1   = (u16*)(ws + 301015040L);    // 4,718,592
  u16* wr2   = (u16*)(ws + 305733632L);    // 4,718,592  (total 310,452,224)

  // prep
  transp_cast_x2<<<dim3(50, 16, 32), 256, 0, stream>>>(ex, qu, xt_e, xt_q);
  cast_w<<<dim3(512), 256, 0, stream>>>(w_e, w_q, w_ebf, w_qbf);
  repack_wc<<<dim3(9216, 2), 256, 0, stream>>>(w_c1, w_c2, wr1, wr2);
  // zero att_e, att_q, Zrow, Zcol (contiguous): 58,007,552 B
  zero_mem<<<dim3(2048), 256, 0, stream>>>((uint4*)att_e, 3625472L);

  // K1: corr[b][n][o] = sum_c xt[n,c] * w[o,c]   (both e and q in one grid)
  gemm_bt64<0><<<dim3(13, 2, 32), 256, 0, stream>>>(
      xt_e, w_ebf, ecorr, xt_q, w_qbf, qcorr, 1600, 256, 512, 819200L, 0L, 409600L);

  // K2: E/ET/Zrow/Zcol fused
  gemm_corr_exp<<<dim3(13, 13, 16), 256, 0, stream>>>(ecorr, qcorr, E, ET, Zrow, Zcol);

  // K3: scale inputs by softmax denominators
  u16* ebf = xt_e;
  u16* qbf = xt_q;
  scale_div<<<dim3(51200, 2), 256, 0, stream>>>(ex, qu, Zcol, Zrow, ebf, qbf);

  // K4: att_q[p][c] = sum_i E[p,i]*ebf[c,i] ; att_e[p][c] = sum_i ET[p,i]*qbf[c,i]
  gemm_bt64<2><<<dim3(13, 4, 32), 256, 0, stream>>>(
      E, ebf, att_q, ET, qbf, att_e, 1600, 512, 1600, 2560000L, 819200L, 903168L);

  // K5: both convs, 256(o)x224(p) 4-phase; ch 0..511 = conv(att_e, w_c1), 512.. = conv(att_q, w_c2)
  conv_gemm4p<<<dim3(8, 2, 32), 512, 0, stream>>>(wr1, att_e, wr2, att_q, out);
}

// Round 3
// 835.921 us; speedup vs baseline: 1.1131x; 1.0025x over previous
//
#include <hip/hip_runtime.h>

typedef unsigned short u16;
typedef __attribute__((ext_vector_type(8))) short bf16x8;
typedef __attribute__((ext_vector_type(4))) float f32x4;

__device__ __forceinline__ u16 f2bf(float f) {
  union { float f; unsigned u; } v; v.f = f;
  unsigned u = v.u;
  u += 0x7fffu + ((u >> 16) & 1u);
  return (u16)(u >> 16);
}

__device__ __forceinline__ void gll16(const void* g, void* l) {
  __builtin_amdgcn_global_load_lds(
      (const __attribute__((address_space(1))) void*)g,
      (__attribute__((address_space(3))) void*)l, 16, 0, 0);
}

// ---------------------------------------------------------------------------
// P1: x[b][c][n] f32 -> xt[b][n][c] bf16   (C=512, N=1600), both inputs
// ---------------------------------------------------------------------------
__global__ __launch_bounds__(256) void transp_cast_x2(const float* __restrict__ ex,
                                                      const float* __restrict__ qu,
                                                      u16* __restrict__ xte,
                                                      u16* __restrict__ xtq) {
  __shared__ float t[32][33];
  int z = blockIdx.z;
  int b = z & 15;
  const float* xb = (z < 16 ? ex : qu) + (size_t)b * 819200;
  u16* xtb = (z < 16 ? xte : xtq) + (size_t)b * 819200;
  int n0 = blockIdx.x * 32, c0 = blockIdx.y * 32;
  int tx = threadIdx.x & 31, ty = threadIdx.x >> 5;
#pragma unroll
  for (int k = 0; k < 4; k++) {
    int c = ty + k * 8;
    t[c][tx] = xb[(size_t)(c0 + c) * 1600 + n0 + tx];
  }
  __syncthreads();
#pragma unroll
  for (int k = 0; k < 4; k++) {
    int n = ty + k * 8;
    xtb[(size_t)(n0 + n) * 512 + c0 + tx] = f2bf(t[tx][n]);
  }
}

// P2: cast w_e / w_q (256x512 each) to bf16
__global__ void cast_w(const float* __restrict__ we, const float* __restrict__ wq,
                       u16* __restrict__ oe, u16* __restrict__ oq) {
  int i = blockIdx.x * 256 + threadIdx.x;
  oe[i] = f2bf(we[i]);
  oq[i] = f2bf(wq[i]);
}

// P3: w[o][c][ky][kx] f32 -> wr[o][t*512+c] bf16 (both conv weights)
__global__ void repack_wc(const float* __restrict__ w1, const float* __restrict__ w2,
                          u16* __restrict__ o1, u16* __restrict__ o2) {
  const float* w = blockIdx.y ? w2 : w1;
  u16* wr = blockIdx.y ? o2 : o1;
  int idx = blockIdx.x * 256 + threadIdx.x;  // 2359296 total
  int o = idx / 4608;
  int r = idx - o * 4608;
  int t = r >> 9;
  int c = r & 511;
  wr[idx] = f2bf(w[o * 4608 + c * 9 + t]);
}

// P4: zero att buffers + Z buffers
__global__ void zero_mem(uint4* __restrict__ p, long n) {
  long i = (long)blockIdx.x * blockDim.x + threadIdx.x;
  long stride = (long)gridDim.x * blockDim.x;
  uint4 z; z.x = 0; z.y = 0; z.z = 0; z.w = 0;
  for (; i < n; i += stride) p[i] = z;
}

// ---------------------------------------------------------------------------
// Generic A*B^T bf16 GEMM, 128x128 tile, BK=64, XOR-swizzled LDS,
// dual problem sets selected by blockIdx.z (z<16 -> set1, else set2).
// MODE 0: store bf16 C[i*N+j].  MODE 2: store bf16 to padded pixel layout.
// ---------------------------------------------------------------------------
template <int MODE>
__global__ __launch_bounds__(256) void gemm_bt64(
    const u16* __restrict__ A, const u16* __restrict__ B, u16* __restrict__ C,
    const u16* __restrict__ A2, const u16* __restrict__ B2, u16* __restrict__ C2,
    int M, int N, int K, long sA, long sB, long sC) {
  __shared__ u16 lds_a[128 * 64];
  __shared__ u16 lds_b[128 * 64];
  int tid = threadIdx.x;
  int z = blockIdx.z, b = z & 15;
  const u16* Ab = (z < 16 ? A : A2) + (size_t)b * sA;
  const u16* Bb = (z < 16 ? B : B2) + (size_t)b * sB;
  u16* Cb = (z < 16 ? C : C2) + (size_t)b * sC;
  int m0 = blockIdx.x * 128, n0 = blockIdx.y * 128;

  int rsub = tid >> 3;                     // 0..31
  int gch = (tid & 7) ^ (rsub & 7);        // swizzled 16B chunk to fetch
  long Kb = (long)K * 2;
  const char* pa[4];
  const char* pb[4];
#pragma unroll
  for (int c = 0; c < 4; c++) {
    int ra = m0 + 32 * c + rsub; ra = ra < M ? ra : M - 1;
    int rb = n0 + 32 * c + rsub; rb = rb < N ? rb : N - 1;
    pa[c] = (const char*)Ab + (long)ra * Kb + gch * 16;
    pb[c] = (const char*)Bb + (long)rb * Kb + gch * 16;
  }

  const f32x4 fzero = {0.f, 0.f, 0.f, 0.f};
  f32x4 acc[4][4];
#pragma unroll
  for (int mi = 0; mi < 4; mi++)
#pragma unroll
    for (int ni = 0; ni < 4; ni++) acc[mi][ni] = fzero;

  int wid = tid >> 6, lane = tid & 63;
  int wm = wid & 1, wn = wid >> 1;
  int lrow = lane & 15, lquad = lane >> 4;
  int sl = lrow & 7;

  int ksteps = K >> 6;
  for (int ks = 0; ks < ksteps; ks++) {
#pragma unroll
    for (int c = 0; c < 4; c++) {
      gll16(pa[c], (char*)lds_a + c * 4096 + tid * 16);
      gll16(pb[c], (char*)lds_b + c * 4096 + tid * 16);
      pa[c] += 128; pb[c] += 128;
    }
    __syncthreads();
#pragma unroll
    for (int k2 = 0; k2 < 2; k2++) {
      int sel = ((k2 << 2) | lquad) ^ sl;
      bf16x8 bv[4];
#pragma unroll
      for (int ni = 0; ni < 4; ni++) {
        int rowb = wn * 64 + ni * 16 + lrow;
        bv[ni] = *(const bf16x8*)((const char*)lds_b + rowb * 128 + sel * 16);
      }
#pragma unroll
      for (int mi = 0; mi < 4; mi++) {
        int rowa = wm * 64 + mi * 16 + lrow;
        bf16x8 av = *(const bf16x8*)((const char*)lds_a + rowa * 128 + sel * 16);
#pragma unroll
        for (int ni = 0; ni < 4; ni++)
          acc[mi][ni] =
              __builtin_amdgcn_mfma_f32_16x16x32_bf16(av, bv[ni], acc[mi][ni], 0, 0, 0);
      }
    }
    __syncthreads();
  }

#pragma unroll
  for (int mi = 0; mi < 4; mi++) {
#pragma unroll
    for (int r = 0; r < 4; r++) {
      int i = m0 + wm * 64 + mi * 16 + lquad * 4 + r;
      if (i >= M) continue;
#pragma unroll
      for (int ni = 0; ni < 4; ni++) {
        int j = n0 + wn * 64 + ni * 16 + lrow;
        if (j >= N) continue;
        float v = acc[mi][ni][r];
        if (MODE == 2) {
          int y = i / 40, x = i - y * 40;
          Cb[(size_t)((y + 1) * 42 + (x + 1)) * 512 + j] = f2bf(v);
        } else {
          Cb[(size_t)i * N + j] = f2bf(v);
        }
      }
    }
  }
}

// ---------------------------------------------------------------------------
// K2: E = exp(ecorr * qcorr^T)  [1600x1600 per batch, K=256]
// Fused epilogue: E (coalesced 16B rows), ET (LDS transpose), Zrow/Zcol sums
// via shuffle + atomics.
// ---------------------------------------------------------------------------
__global__ __launch_bounds__(256) void gemm_corr_exp(
    const u16* __restrict__ A, const u16* __restrict__ B, u16* __restrict__ E,
    u16* __restrict__ ET, float* __restrict__ Zrow, float* __restrict__ Zcol) {
  __shared__ u16 lds_a[128 * 64];
  __shared__ u16 lds_b[128 * 64];
  int tid = threadIdx.x;
  int b = blockIdx.z;
  const u16* Ab = A + (size_t)b * 409600;
  const u16* Bb = B + (size_t)b * 409600;
  u16* Eb = E + (size_t)b * 2560000;
  u16* ETb = ET + (size_t)b * 2560000;
  int m0 = blockIdx.x * 128, n0 = blockIdx.y * 128;

  int rsub = tid >> 3;
  int gch = (tid & 7) ^ (rsub & 7);
  const char* pa[4];
  const char* pb[4];
#pragma unroll
  for (int c = 0; c < 4; c++) {
    int ra = m0 + 32 * c + rsub; ra = ra < 1600 ? ra : 1599;
    int rb = n0 + 32 * c + rsub; rb = rb < 1600 ? rb : 1599;
    pa[c] = (const char*)(Ab + (size_t)ra * 256) + gch * 16;
    pb[c] = (const char*)(Bb + (size_t)rb * 256) + gch * 16;
  }

  const f32x4 fzero = {0.f, 0.f, 0.f, 0.f};
  f32x4 acc[4][4];
#pragma unroll
  for (int mi = 0; mi < 4; mi++)
#pragma unroll
    for (int ni = 0; ni < 4; ni++) acc[mi][ni] = fzero;

  int wid = tid >> 6, lane = tid & 63;
  int wm = wid & 1, wn = wid >> 1;
  int lrow = lane & 15, lquad = lane >> 4;
  int sl = lrow & 7;

  for (int ks = 0; ks < 4; ks++) {
#pragma unroll
    for (int c = 0; c < 4; c++) {
      gll16(pa[c], (char*)lds_a + c * 4096 + tid * 16);
      gll16(pb[c], (char*)lds_b + c * 4096 + tid * 16);
      pa[c] += 128; pb[c] += 128;
    }
    __syncthreads();
#pragma unroll
    for (int k2 = 0; k2 < 2; k2++) {
      int sel = ((k2 << 2) | lquad) ^ sl;
      bf16x8 bv[4];
#pragma unroll
      for (int ni = 0; ni < 4; ni++) {
        int rowb = wn * 64 + ni * 16 + lrow;
        bv[ni] = *(const bf16x8*)((const char*)lds_b + rowb * 128 + sel * 16);
      }
#pragma unroll
      for (int mi = 0; mi < 4; mi++) {
        int rowa = wm * 64 + mi * 16 + lrow;
        bf16x8 av = *(const bf16x8*)((const char*)lds_a + rowa * 128 + sel * 16);
#pragma unroll
        for (int ni = 0; ni < 4; ni++)
          acc[mi][ni] =
              __builtin_amdgcn_mfma_f32_16x16x32_bf16(av, bv[ni], acc[mi][ni], 0, 0, 0);
      }
    }
    __syncthreads();
  }

  // ---- fused epilogue: exp, E store, ET store (LDS transpose), Z sums ----
  const int TS = 136;  // padded LDS row stride (u16) for 32x128 slice
  u16* T = lds_a;
  float colacc[4] = {0.f, 0.f, 0.f, 0.f};
#pragma unroll
  for (int s = 0; s < 4; s++) {
    if (wm == (s >> 1)) {
      int smi0 = (s & 1) * 2;
#pragma unroll
      for (int mi2 = 0; mi2 < 2; mi2++) {
        int mi = smi0 + mi2;
        float rowp[4] = {0.f, 0.f, 0.f, 0.f};
#pragma unroll
        for (int ni = 0; ni < 4; ni++) {
          int j = n0 + wn * 64 + ni * 16 + lrow;
          bool jv = j < 1600;
#pragma unroll
          for (int r = 0; r < 4; r++) {
            int i = m0 + wm * 64 + mi * 16 + lquad * 4 + r;
            float e = __expf(acc[mi][ni][r]);
            T[(mi2 * 16 + lquad * 4 + r) * TS + wn * 64 + ni * 16 + lrow] = f2bf(e);
            rowp[r] += jv ? e : 0.f;
            colacc[ni] += (i < 1600) ? e : 0.f;
          }
        }
#pragma unroll
        for (int r = 0; r < 4; r++) {
          float v = rowp[r];
          v += __shfl_xor(v, 1);
          v += __shfl_xor(v, 2);
          v += __shfl_xor(v, 4);
          v += __shfl_xor(v, 8);
          int i = m0 + wm * 64 + mi * 16 + lquad * 4 + r;
          if (lrow == 0 && i < 1600) atomicAdd(&Zrow[b * 1600 + i], v);
        }
      }
    }
    __syncthreads();
    // E rows: 32 rows x 128 cols, 16B coalesced stores
#pragma unroll
    for (int p = 0; p < 2; p++) {
      int jj = tid + p * 256;
      int ml = jj >> 4, n8 = jj & 15;
      int gi = m0 + s * 32 + ml, gj = n0 + n8 * 8;
      if (gi < 1600 && gj < 1600)
        *(uint4*)(Eb + (size_t)gi * 1600 + gj) = *(const uint4*)&T[ml * TS + n8 * 8];
    }
    // ET rows: transposed, 8B stores
#pragma unroll
    for (int p = 0; p < 4; p++) {
      int jj = tid + p * 256;
      int n = jj >> 3, m4 = jj & 7;
      int gm = m0 + s * 32 + m4 * 4, gn = n0 + n;
      if (gn < 1600 && gm < 1600) {
        ushort4 v;
        v.x = T[(m4 * 4 + 0) * TS + n];
        v.y = T[(m4 * 4 + 1) * TS + n];
        v.z = T[(m4 * 4 + 2) * TS + n];
        v.w = T[(m4 * 4 + 3) * TS + n];
        *(ushort4*)(ETb + (size_t)gn * 1600 + gm) = v;
      }
    }
    __syncthreads();
  }
#pragma unroll
  for (int ni = 0; ni < 4; ni++) {
    float v = colacc[ni];
    v += __shfl_xor(v, 16);
    v += __shfl_xor(v, 32);
    int j = n0 + wn * 64 + ni * 16 + lrow;
    if (lquad == 0 && j < 1600) atomicAdd(&Zcol[b * 1600 + j], v);
  }
}

// K3: out[idx] = bf16( x[idx] / Z[b][pixel] )   (both inputs via blockIdx.y)
__global__ void scale_div(const float* __restrict__ ex, const float* __restrict__ qu,
                          const float* __restrict__ Zcol, const float* __restrict__ Zrow,
                          u16* __restrict__ ebf, u16* __restrict__ qbf) {
  const float* x; const float* Z; u16* o;
  if (blockIdx.y == 0) { x = ex; Z = Zcol; o = ebf; }
  else { x = qu; Z = Zrow; o = qbf; }
  size_t idx = (size_t)blockIdx.x * 256 + threadIdx.x;  // 13,107,200
  int b = (int)(idx / 819200);
  int i = (int)(idx % 1600);
  o[idx] = f2bf(x[idx] / Z[b * 1600 + i]);
}

// ---------------------------------------------------------------------------
// K5: both 3x3 convs as 256(o)x224(p)-tile 4-phase SINGLE-BARRIER GEMM.
// W: [512][4608] (k=t*512+c), ATT: padded [b][42*42][512] bf16. out fp32.
//
// One s_barrier per phase; stage in phase P targets region R[(P+2)%4], last
// read in phase P-2 (all waves provably past it: skew < 1 phase). vmcnt(8)
// before the barrier guarantees R[P%4] (staged at P-2, 3rd-oldest) landed.
// ds_reads are C++ loads -> compiler emits fine-grained lgkmcnt, so early
// MFMAs overlap the LDS drain; cross-wave skew overlaps LDS pipe (1056
// cyc/CU/phase) with MFMA pipe (1086 cyc/SIMD/phase) instead of serializing.
// Grid: 8 p-tiles x 2 o-tiles x 32 z = 512 blocks = exactly 2 full CU rounds.
// ---------------------------------------------------------------------------
__global__ __launch_bounds__(512, 2) void conv_gemm1b(
    const u16* __restrict__ W1, const u16* __restrict__ ATT1,
    const u16* __restrict__ W2, const u16* __restrict__ ATT2,
    float* __restrict__ out) {
  __shared__ u16 ldsA[32768];  // [2][2][256 rows][32 elems]
  __shared__ u16 ldsB[32768];  // [2][2][256 rows][32 elems] (rows 224+ dummy)
  int tid = threadIdx.x;
  int z = blockIdx.z, b = z & 15, sel2 = z >> 4;
  const u16* W = sel2 ? W2 : W1;
  const u16* attb = (sel2 ? ATT2 : ATT1) + (size_t)b * 903168;
  float* outb = out + (size_t)b * 1638400 + (size_t)(sel2 ? 512 : 0) * 1600;
  int p0 = blockIdx.x * 224, o0 = blockIdx.y * 256;

  // ---- staging setup (source pre-swizzle, linear LDS dest) ----
  int rl = tid >> 2;                      // local row 0..127 (second call +128)
  int cs = (tid & 3) ^ ((rl >> 1) & 3);   // swizzled 16B source chunk (of 4)
  const char* pA0 = (const char*)(W + (size_t)(o0 + rl) * 4608) + cs * 16;
  const char* pA1 = pA0 + 128 * 9216;
  int pp0 = p0 + rl; pp0 = pp0 < 1600 ? pp0 : 1599;
  int y0 = pp0 / 40, x0 = pp0 - y0 * 40;
  const char* pB0 = (const char*)(attb + (size_t)(y0 * 42 + x0) * 512) + cs * 16;
  int pp1 = p0 + 128 + rl; pp1 = pp1 < 1600 ? pp1 : 1599;  // rows 224+ dummy
  int y1 = pp1 / 40, x1 = pp1 - y1 * 40;
  const char* pB1 = (const char*)(attb + (size_t)(y1 * 42 + x1) * 512) + cs * 16;

  char* ldsAb = (char*)ldsA;
  char* ldsBb = (char*)ldsB;
  int dstT = tid * 16;

#define STAGE_A(d, kh, kt)                                              \
  {                                                                     \
    int ko = (kt) * 128 + (kh) * 64;                                    \
    gll16(pA0 + ko, ldsAb + ((d) * 2 + (kh)) * 16384 + dstT);           \
    gll16(pA1 + ko, ldsAb + ((d) * 2 + (kh)) * 16384 + 8192 + dstT);    \
  }
#define STAGE_B(d, kh, kt)                                              \
  {                                                                     \
    int tp = (kt) >> 3;                                                 \
    int ty = (tp * 11) >> 5;                                            \
    int tx = tp - ty * 3;                                               \
    int ko = (ty * 42 + tx) * 1024 + ((kt) & 7) * 128 + (kh) * 64;      \
    gll16(pB0 + ko, ldsBb + ((d) * 2 + (kh)) * 16384 + dstT);           \
    gll16(pB1 + ko, ldsBb + ((d) * 2 + (kh)) * 16384 + 8192 + dstT);    \
  }
#define STAGE_U(d, kh, kt) { STAGE_A(d, kh, kt); STAGE_B(d, kh, kt); }

  // ---- compute-side lane mapping ----
  int wid = tid >> 6, lane = tid & 63;
  int wm = wid & 3, wn = wid >> 2;             // 4 o-waves x 2 p-waves
  int lrow = lane & 15, lquad = lane >> 4;
  int csel = (lquad ^ ((lrow >> 1) & 3)) << 4;
  int aBase = (wm * 64 + lrow) * 64 + csel;    // byte offset within region
  int bBase = (wn * 112 + lrow) * 64 + csel;

  const f32x4 fzero = {0.f, 0.f, 0.f, 0.f};
  f32x4 acc[4][7];
#pragma unroll
  for (int mi = 0; mi < 4; mi++)
#pragma unroll
    for (int ni = 0; ni < 7; ni++) acc[mi][ni] = fzero;

  // ---- prologue: R0=(0,k0)<-kt0, R1=(0,k1)<-kt0 ----
  STAGE_U(0, 0, 0);
  STAGE_U(0, 1, 0);

#define MROW(mi, av)                                                                   \
  acc[mi][0] = __builtin_amdgcn_mfma_f32_16x16x32_bf16(av, bv0, acc[mi][0], 0, 0, 0);  \
  acc[mi][1] = __builtin_amdgcn_mfma_f32_16x16x32_bf16(av, bv1, acc[mi][1], 0, 0, 0);  \
  acc[mi][2] = __builtin_amdgcn_mfma_f32_16x16x32_bf16(av, bv2, acc[mi][2], 0, 0, 0);  \
  acc[mi][3] = __builtin_amdgcn_mfma_f32_16x16x32_bf16(av, bv3, acc[mi][3], 0, 0, 0);  \
  acc[mi][4] = __builtin_amdgcn_mfma_f32_16x16x32_bf16(av, bv4, acc[mi][4], 0, 0, 0);  \
  acc[mi][5] = __builtin_amdgcn_mfma_f32_16x16x32_bf16(av, bv5, acc[mi][5], 0, 0, 0);  \
  acc[mi][6] = __builtin_amdgcn_mfma_f32_16x16x32_bf16(av, bv6, acc[mi][6], 0, 0, 0);

// Single barrier per phase. STG stages R[(P+2)%4]; vmcnt(8) leaves the two
// newest stages (for P+1, P+2) in flight and guarantees R[P%4] landed.
#define PHASE(d, kh, STG)                                                      \
  {                                                                            \
    STG;                                                                       \
    asm volatile("s_waitcnt vmcnt(8)" ::: "memory");                           \
    __builtin_amdgcn_s_barrier();                                              \
    const char* ra_ = ldsAb + ((d) * 2 + (kh)) * 16384 + aBase;                \
    const char* rb_ = ldsBb + ((d) * 2 + (kh)) * 16384 + bBase;                \
    bf16x8 av0 = *(const bf16x8*)(ra_);                                        \
    bf16x8 av1 = *(const bf16x8*)(ra_ + 1024);                                 \
    bf16x8 av2 = *(const bf16x8*)(ra_ + 2048);                                 \
    bf16x8 av3 = *(const bf16x8*)(ra_ + 3072);                                 \
    bf16x8 bv0 = *(const bf16x8*)(rb_);                                        \
    bf16x8 bv1 = *(const bf16x8*)(rb_ + 1024);                                 \
    bf16x8 bv2 = *(const bf16x8*)(rb_ + 2048);                                 \
    bf16x8 bv3 = *(const bf16x8*)(rb_ + 3072);                                 \
    bf16x8 bv4 = *(const bf16x8*)(rb_ + 4096);                                 \
    bf16x8 bv5 = *(const bf16x8*)(rb_ + 5120);                                 \
    bf16x8 bv6 = *(const bf16x8*)(rb_ + 6144);                                 \
    __builtin_amdgcn_s_setprio(1);                                             \
    MROW(0, av0)                                                               \
    MROW(1, av1)                                                               \
    MROW(2, av2)                                                               \
    MROW(3, av3)                                                               \
    __builtin_amdgcn_s_setprio(0);                                             \
  }

#pragma unroll 1
  for (int it = 0; it < 36; ++it) {
    int kt0 = it * 2;
    int kt1 = kt0 + 1;
    int kt2 = it < 35 ? kt0 + 2 : 71;  // clamped; garbage on last iter, unread
    PHASE(0, 0, STAGE_U(1, 0, kt1));   // P%4==0: stage R2 (read at P+2)
    PHASE(0, 1, STAGE_U(1, 1, kt1));   // P%4==1: stage R3
    PHASE(1, 0, STAGE_U(0, 0, kt2));   // P%4==2: stage R0 (next iter)
    PHASE(1, 1, STAGE_U(0, 1, kt2));   // P%4==3: stage R1
  }

#undef PHASE
#undef MROW
#undef STAGE_U
#undef STAGE_A
#undef STAGE_B

  // ---- epilogue: fp32 stores, guard pixel tail ----
#pragma unroll
  for (int mi = 0; mi < 4; mi++) {
#pragma unroll
    for (int r = 0; r < 4; r++) {
      int o = o0 + wm * 64 + mi * 16 + lquad * 4 + r;
      float* orow = outb + (size_t)o * 1600;
#pragma unroll
      for (int ni = 0; ni < 7; ni++) {
        int p = p0 + wn * 112 + ni * 16 + lrow;
        if (p < 1600) orow[p] = acc[mi][ni][r];
      }
    }
  }
}

// ---------------------------------------------------------------------------
extern "C" void kernel_launch(void* const* d_in, const int* in_sizes, int n_in,
                              void* d_out, int out_size, void* d_ws, size_t ws_size,
                              hipStream_t stream) {
  const float* ex = (const float*)d_in[0];
  const float* qu = (const float*)d_in[1];
  const float* w_e = (const float*)d_in[2];
  const float* w_q = (const float*)d_in[3];
  const float* w_c1 = (const float*)d_in[4];
  const float* w_c2 = (const float*)d_in[5];
  float* out = (float*)d_out;
  char* ws = (char*)d_ws;

  u16* E     = (u16*)(ws + 0L);            // 81,920,000
  u16* ET    = (u16*)(ws + 81920000L);     // 81,920,000
  u16* xt_e  = (u16*)(ws + 163840000L);    // 26,214,400 (reused as ebf)
  u16* xt_q  = (u16*)(ws + 190054400L);    // 26,214,400 (reused as qbf)
  u16* ecorr = (u16*)(ws + 216268800L);    // 13,107,200
  u16* qcorr = (u16*)(ws + 229376000L);    // 13,107,200
  u16* att_e = (u16*)(ws + 242483200L);    // 28,901,376
  u16* att_q = (u16*)(ws + 271384576L);    // 28,901,376
  float* Zrow = (float*)(ws + 300285952L); // 102,400
  float* Zcol = (float*)(ws + 300388352L); // 102,400
  u16* w_ebf = (u16*)(ws + 300490752L);    // 262,144
  u16* w_qbf = (u16*)(ws + 300752896L);    // 262,144
  u16* wr1   = (u16*)(ws + 301015040L);    // 4,718,592
  u16* wr2   = (u16*)(ws + 305733632L);    // 4,718,592  (total 310,452,224)

  // prep
  transp_cast_x2<<<dim3(50, 16, 32), 256, 0, stream>>>(ex, qu, xt_e, xt_q);
  cast_w<<<dim3(512), 256, 0, stream>>>(w_e, w_q, w_ebf, w_qbf);
  repack_wc<<<dim3(9216, 2), 256, 0, stream>>>(w_c1, w_c2, wr1, wr2);
  // zero att_e, att_q, Zrow, Zcol (contiguous): 58,007,552 B
  zero_mem<<<dim3(2048), 256, 0, stream>>>((uint4*)att_e, 3625472L);

  // K1: corr[b][n][o] = sum_c xt[n,c] * w[o,c]   (both e and q in one grid)
  gemm_bt64<0><<<dim3(13, 2, 32), 256, 0, stream>>>(
      xt_e, w_ebf, ecorr, xt_q, w_qbf, qcorr, 1600, 256, 512, 819200L, 0L, 409600L);

  // K2: E/ET/Zrow/Zcol fused
  gemm_corr_exp<<<dim3(13, 13, 16), 256, 0, stream>>>(ecorr, qcorr, E, ET, Zrow, Zcol);

  // K3: scale inputs by softmax denominators
  u16* ebf = xt_e;
  u16* qbf = xt_q;
  scale_div<<<dim3(51200, 2), 256, 0, stream>>>(ex, qu, Zcol, Zrow, ebf, qbf);

  // K4: att_q[p][c] = sum_i E[p,i]*ebf[c,i] ; att_e[p][c] = sum_i ET[p,i]*qbf[c,i]
  gemm_bt64<2><<<dim3(13, 4, 32), 256, 0, stream>>>(
      E, ebf, att_q, ET, qbf, att_e, 1600, 512, 1600, 2560000L, 819200L, 903168L);

  // K5: both convs, 256(o)x224(p) single-barrier 4-phase
  conv_gemm1b<<<dim3(8, 2, 32), 512, 0, stream>>>(wr1, att_e, wr2, att_q, out);
}

// Round 4
// 830.980 us; speedup vs baseline: 1.1197x; 1.0059x over previous
//
#include <hip/hip_runtime.h>

typedef unsigned short u16;
typedef __attribute__((ext_vector_type(8))) short bf16x8;
typedef __attribute__((ext_vector_type(4))) float f32x4;

__device__ __forceinline__ u16 f2bf(float f) {
  union { float f; unsigned u; } v; v.f = f;
  unsigned u = v.u;
  u += 0x7fffu + ((u >> 16) & 1u);
  return (u16)(u >> 16);
}

__device__ __forceinline__ void gll16(const void* g, void* l) {
  __builtin_amdgcn_global_load_lds(
      (const __attribute__((address_space(1))) void*)g,
      (__attribute__((address_space(3))) void*)l, 16, 0, 0);
}

// ---------------------------------------------------------------------------
// P1: x[b][c][n] f32 -> xt[b][n][c] bf16   (C=512, N=1600), both inputs
// ---------------------------------------------------------------------------
__global__ __launch_bounds__(256) void transp_cast_x2(const float* __restrict__ ex,
                                                      const float* __restrict__ qu,
                                                      u16* __restrict__ xte,
                                                      u16* __restrict__ xtq) {
  __shared__ float t[32][33];
  int z = blockIdx.z;
  int b = z & 15;
  const float* xb = (z < 16 ? ex : qu) + (size_t)b * 819200;
  u16* xtb = (z < 16 ? xte : xtq) + (size_t)b * 819200;
  int n0 = blockIdx.x * 32, c0 = blockIdx.y * 32;
  int tx = threadIdx.x & 31, ty = threadIdx.x >> 5;
#pragma unroll
  for (int k = 0; k < 4; k++) {
    int c = ty + k * 8;
    t[c][tx] = xb[(size_t)(c0 + c) * 1600 + n0 + tx];
  }
  __syncthreads();
#pragma unroll
  for (int k = 0; k < 4; k++) {
    int n = ty + k * 8;
    xtb[(size_t)(n0 + n) * 512 + c0 + tx] = f2bf(t[tx][n]);
  }
}

// P2: cast w_e / w_q (256x512 each) to bf16
__global__ void cast_w(const float* __restrict__ we, const float* __restrict__ wq,
                       u16* __restrict__ oe, u16* __restrict__ oq) {
  int i = blockIdx.x * 256 + threadIdx.x;
  oe[i] = f2bf(we[i]);
  oq[i] = f2bf(wq[i]);
}

// P3: w[o][c][ky][kx] f32 -> wr[o][t*512+c] bf16 (both conv weights)
__global__ void repack_wc(const float* __restrict__ w1, const float* __restrict__ w2,
                          u16* __restrict__ o1, u16* __restrict__ o2) {
  const float* w = blockIdx.y ? w2 : w1;
  u16* wr = blockIdx.y ? o2 : o1;
  int idx = blockIdx.x * 256 + threadIdx.x;  // 2359296 total
  int o = idx / 4608;
  int r = idx - o * 4608;
  int t = r >> 9;
  int c = r & 511;
  wr[idx] = f2bf(w[o * 4608 + c * 9 + t]);
}

// P4: zero att buffers + Z buffers
__global__ void zero_mem(uint4* __restrict__ p, long n) {
  long i = (long)blockIdx.x * blockDim.x + threadIdx.x;
  long stride = (long)gridDim.x * blockDim.x;
  uint4 z; z.x = 0; z.y = 0; z.z = 0; z.w = 0;
  for (; i < n; i += stride) p[i] = z;
}

// ---------------------------------------------------------------------------
// Generic A*B^T bf16 GEMM, 128x128 tile, BK=64, XOR-swizzled LDS,
// dual problem sets selected by blockIdx.z (z<16 -> set1, else set2).
// MODE 0: store bf16 C[i*N+j].  MODE 2: store bf16 to padded pixel layout.
// ---------------------------------------------------------------------------
template <int MODE>
__global__ __launch_bounds__(256) void gemm_bt64(
    const u16* __restrict__ A, const u16* __restrict__ B, u16* __restrict__ C,
    const u16* __restrict__ A2, const u16* __restrict__ B2, u16* __restrict__ C2,
    int M, int N, int K, long sA, long sB, long sC) {
  __shared__ u16 lds_a[128 * 64];
  __shared__ u16 lds_b[128 * 64];
  int tid = threadIdx.x;
  int z = blockIdx.z, b = z & 15;
  const u16* Ab = (z < 16 ? A : A2) + (size_t)b * sA;
  const u16* Bb = (z < 16 ? B : B2) + (size_t)b * sB;
  u16* Cb = (z < 16 ? C : C2) + (size_t)b * sC;
  int m0 = blockIdx.x * 128, n0 = blockIdx.y * 128;

  int rsub = tid >> 3;                     // 0..31
  int gch = (tid & 7) ^ (rsub & 7);        // swizzled 16B chunk to fetch
  long Kb = (long)K * 2;
  const char* pa[4];
  const char* pb[4];
#pragma unroll
  for (int c = 0; c < 4; c++) {
    int ra = m0 + 32 * c + rsub; ra = ra < M ? ra : M - 1;
    int rb = n0 + 32 * c + rsub; rb = rb < N ? rb : N - 1;
    pa[c] = (const char*)Ab + (long)ra * Kb + gch * 16;
    pb[c] = (const char*)Bb + (long)rb * Kb + gch * 16;
  }

  const f32x4 fzero = {0.f, 0.f, 0.f, 0.f};
  f32x4 acc[4][4];
#pragma unroll
  for (int mi = 0; mi < 4; mi++)
#pragma unroll
    for (int ni = 0; ni < 4; ni++) acc[mi][ni] = fzero;

  int wid = tid >> 6, lane = tid & 63;
  int wm = wid & 1, wn = wid >> 1;
  int lrow = lane & 15, lquad = lane >> 4;
  int sl = lrow & 7;

  int ksteps = K >> 6;
  for (int ks = 0; ks < ksteps; ks++) {
#pragma unroll
    for (int c = 0; c < 4; c++) {
      gll16(pa[c], (char*)lds_a + c * 4096 + tid * 16);
      gll16(pb[c], (char*)lds_b + c * 4096 + tid * 16);
      pa[c] += 128; pb[c] += 128;
    }
    __syncthreads();
#pragma unroll
    for (int k2 = 0; k2 < 2; k2++) {
      int sel = ((k2 << 2) | lquad) ^ sl;
      bf16x8 bv[4];
#pragma unroll
      for (int ni = 0; ni < 4; ni++) {
        int rowb = wn * 64 + ni * 16 + lrow;
        bv[ni] = *(const bf16x8*)((const char*)lds_b + rowb * 128 + sel * 16);
      }
#pragma unroll
      for (int mi = 0; mi < 4; mi++) {
        int rowa = wm * 64 + mi * 16 + lrow;
        bf16x8 av = *(const bf16x8*)((const char*)lds_a + rowa * 128 + sel * 16);
#pragma unroll
        for (int ni = 0; ni < 4; ni++)
          acc[mi][ni] =
              __builtin_amdgcn_mfma_f32_16x16x32_bf16(av, bv[ni], acc[mi][ni], 0, 0, 0);
      }
    }
    __syncthreads();
  }

#pragma unroll
  for (int mi = 0; mi < 4; mi++) {
#pragma unroll
    for (int r = 0; r < 4; r++) {
      int i = m0 + wm * 64 + mi * 16 + lquad * 4 + r;
      if (i >= M) continue;
#pragma unroll
      for (int ni = 0; ni < 4; ni++) {
        int j = n0 + wn * 64 + ni * 16 + lrow;
        if (j >= N) continue;
        float v = acc[mi][ni][r];
        if (MODE == 2) {
          int y = i / 40, x = i - y * 40;
          Cb[(size_t)((y + 1) * 42 + (x + 1)) * 512 + j] = f2bf(v);
        } else {
          Cb[(size_t)i * N + j] = f2bf(v);
        }
      }
    }
  }
}

// ---------------------------------------------------------------------------
// K2: E = exp(ecorr * qcorr^T)  [1600x1600 per batch, K=256]
// Fused epilogue: E (coalesced 16B rows), ET (LDS transpose), Zrow/Zcol sums
// via shuffle + atomics.
// ---------------------------------------------------------------------------
__global__ __launch_bounds__(256) void gemm_corr_exp(
    const u16* __restrict__ A, const u16* __restrict__ B, u16* __restrict__ E,
    u16* __restrict__ ET, float* __restrict__ Zrow, float* __restrict__ Zcol) {
  __shared__ u16 lds_a[128 * 64];
  __shared__ u16 lds_b[128 * 64];
  int tid = threadIdx.x;
  int b = blockIdx.z;
  const u16* Ab = A + (size_t)b * 409600;
  const u16* Bb = B + (size_t)b * 409600;
  u16* Eb = E + (size_t)b * 2560000;
  u16* ETb = ET + (size_t)b * 2560000;
  int m0 = blockIdx.x * 128, n0 = blockIdx.y * 128;

  int rsub = tid >> 3;
  int gch = (tid & 7) ^ (rsub & 7);
  const char* pa[4];
  const char* pb[4];
#pragma unroll
  for (int c = 0; c < 4; c++) {
    int ra = m0 + 32 * c + rsub; ra = ra < 1600 ? ra : 1599;
    int rb = n0 + 32 * c + rsub; rb = rb < 1600 ? rb : 1599;
    pa[c] = (const char*)(Ab + (size_t)ra * 256) + gch * 16;
    pb[c] = (const char*)(Bb + (size_t)rb * 256) + gch * 16;
  }

  const f32x4 fzero = {0.f, 0.f, 0.f, 0.f};
  f32x4 acc[4][4];
#pragma unroll
  for (int mi = 0; mi < 4; mi++)
#pragma unroll
    for (int ni = 0; ni < 4; ni++) acc[mi][ni] = fzero;

  int wid = tid >> 6, lane = tid & 63;
  int wm = wid & 1, wn = wid >> 1;
  int lrow = lane & 15, lquad = lane >> 4;
  int sl = lrow & 7;

  for (int ks = 0; ks < 4; ks++) {
#pragma unroll
    for (int c = 0; c < 4; c++) {
      gll16(pa[c], (char*)lds_a + c * 4096 + tid * 16);
      gll16(pb[c], (char*)lds_b + c * 4096 + tid * 16);
      pa[c] += 128; pb[c] += 128;
    }
    __syncthreads();
#pragma unroll
    for (int k2 = 0; k2 < 2; k2++) {
      int sel = ((k2 << 2) | lquad) ^ sl;
      bf16x8 bv[4];
#pragma unroll
      for (int ni = 0; ni < 4; ni++) {
        int rowb = wn * 64 + ni * 16 + lrow;
        bv[ni] = *(const bf16x8*)((const char*)lds_b + rowb * 128 + sel * 16);
      }
#pragma unroll
      for (int mi = 0; mi < 4; mi++) {
        int rowa = wm * 64 + mi * 16 + lrow;
        bf16x8 av = *(const bf16x8*)((const char*)lds_a + rowa * 128 + sel * 16);
#pragma unroll
        for (int ni = 0; ni < 4; ni++)
          acc[mi][ni] =
              __builtin_amdgcn_mfma_f32_16x16x32_bf16(av, bv[ni], acc[mi][ni], 0, 0, 0);
      }
    }
    __syncthreads();
  }

  // ---- fused epilogue: exp, E store, ET store (LDS transpose), Z sums ----
  const int TS = 136;  // padded LDS row stride (u16) for 32x128 slice
  u16* T = lds_a;
  float colacc[4] = {0.f, 0.f, 0.f, 0.f};
#pragma unroll
  for (int s = 0; s < 4; s++) {
    if (wm == (s >> 1)) {
      int smi0 = (s & 1) * 2;
#pragma unroll
      for (int mi2 = 0; mi2 < 2; mi2++) {
        int mi = smi0 + mi2;
        float rowp[4] = {0.f, 0.f, 0.f, 0.f};
#pragma unroll
        for (int ni = 0; ni < 4; ni++) {
          int j = n0 + wn * 64 + ni * 16 + lrow;
          bool jv = j < 1600;
#pragma unroll
          for (int r = 0; r < 4; r++) {
            int i = m0 + wm * 64 + mi * 16 + lquad * 4 + r;
            float e = __expf(acc[mi][ni][r]);
            T[(mi2 * 16 + lquad * 4 + r) * TS + wn * 64 + ni * 16 + lrow] = f2bf(e);
            rowp[r] += jv ? e : 0.f;
            colacc[ni] += (i < 1600) ? e : 0.f;
          }
        }
#pragma unroll
        for (int r = 0; r < 4; r++) {
          float v = rowp[r];
          v += __shfl_xor(v, 1);
          v += __shfl_xor(v, 2);
          v += __shfl_xor(v, 4);
          v += __shfl_xor(v, 8);
          int i = m0 + wm * 64 + mi * 16 + lquad * 4 + r;
          if (lrow == 0 && i < 1600) atomicAdd(&Zrow[b * 1600 + i], v);
        }
      }
    }
    __syncthreads();
    // E rows: 32 rows x 128 cols, 16B coalesced stores
#pragma unroll
    for (int p = 0; p < 2; p++) {
      int jj = tid + p * 256;
      int ml = jj >> 4, n8 = jj & 15;
      int gi = m0 + s * 32 + ml, gj = n0 + n8 * 8;
      if (gi < 1600 && gj < 1600)
        *(uint4*)(Eb + (size_t)gi * 1600 + gj) = *(const uint4*)&T[ml * TS + n8 * 8];
    }
    // ET rows: transposed, 8B stores
#pragma unroll
    for (int p = 0; p < 4; p++) {
      int jj = tid + p * 256;
      int n = jj >> 3, m4 = jj & 7;
      int gm = m0 + s * 32 + m4 * 4, gn = n0 + n;
      if (gn < 1600 && gm < 1600) {
        ushort4 v;
        v.x = T[(m4 * 4 + 0) * TS + n];
        v.y = T[(m4 * 4 + 1) * TS + n];
        v.z = T[(m4 * 4 + 2) * TS + n];
        v.w = T[(m4 * 4 + 3) * TS + n];
        *(ushort4*)(ETb + (size_t)gn * 1600 + gm) = v;
      }
    }
    __syncthreads();
  }
#pragma unroll
  for (int ni = 0; ni < 4; ni++) {
    float v = colacc[ni];
    v += __shfl_xor(v, 16);
    v += __shfl_xor(v, 32);
    int j = n0 + wn * 64 + ni * 16 + lrow;
    if (lquad == 0 && j < 1600) atomicAdd(&Zcol[b * 1600 + j], v);
  }
}

// K3: out[idx] = bf16( x[idx] / Z[b][pixel] )   (both inputs via blockIdx.y)
__global__ void scale_div(const float* __restrict__ ex, const float* __restrict__ qu,
                          const float* __restrict__ Zcol, const float* __restrict__ Zrow,
                          u16* __restrict__ ebf, u16* __restrict__ qbf) {
  const float* x; const float* Z; u16* o;
  if (blockIdx.y == 0) { x = ex; Z = Zcol; o = ebf; }
  else { x = qu; Z = Zrow; o = qbf; }
  size_t idx = (size_t)blockIdx.x * 256 + threadIdx.x;  // 13,107,200
  int b = (int)(idx / 819200);
  int i = (int)(idx % 1600);
  o[idx] = f2bf(x[idx] / Z[b * 1600 + i]);
}

// ---------------------------------------------------------------------------
// K5: both 3x3 convs, 256(o)x224(p) tile, single-barrier 4-phase +
// FRAGMENT PREFETCH: MFMA@P consumes frags read @P-1 (register-resident);
// ds_reads for P+1 issue concurrently with P's MFMAs (no dependency) so the
// LDS pipe (1056 cyc/CU/phase) hides under the MFMA pipe (1086 cyc/phase).
// Rotation: stage@P -> R[(P+2)%4]; frag-read@P -> R[(P+1)%4]; vmcnt(4) at
// barrier P guarantees stage@P-1 landed (region read right after barrier P).
// Clobber-safe: stage@P overwrites R[(P-2)%4], lgkm-consumed before all
// waves passed barrier P-1.
// ---------------------------------------------------------------------------
__global__ __launch_bounds__(512, 2) void conv_gemmpf(
    const u16* __restrict__ W1, const u16* __restrict__ ATT1,
    const u16* __restrict__ W2, const u16* __restrict__ ATT2,
    float* __restrict__ out) {
  __shared__ u16 ldsA[32768];  // [2][2][256 rows][32 elems]
  __shared__ u16 ldsB[32768];  // [2][2][256 rows][32 elems] (rows 224+ dummy)
  int tid = threadIdx.x;
  int z = blockIdx.z, b = z & 15, sel2 = z >> 4;
  const u16* W = sel2 ? W2 : W1;
  const u16* attb = (sel2 ? ATT2 : ATT1) + (size_t)b * 903168;
  float* outb = out + (size_t)b * 1638400 + (size_t)(sel2 ? 512 : 0) * 1600;
  int p0 = blockIdx.x * 224, o0 = blockIdx.y * 256;

  // ---- staging setup (source pre-swizzle, linear LDS dest) ----
  int rl = tid >> 2;                      // local row 0..127 (second call +128)
  int cs = (tid & 3) ^ ((rl >> 1) & 3);   // swizzled 16B source chunk (of 4)
  const char* pA0 = (const char*)(W + (size_t)(o0 + rl) * 4608) + cs * 16;
  const char* pA1 = pA0 + 128 * 9216;
  int pp0 = p0 + rl; pp0 = pp0 < 1600 ? pp0 : 1599;
  int y0 = pp0 / 40, x0 = pp0 - y0 * 40;
  const char* pB0 = (const char*)(attb + (size_t)(y0 * 42 + x0) * 512) + cs * 16;
  int pp1 = p0 + 128 + rl; pp1 = pp1 < 1600 ? pp1 : 1599;  // rows 224+ dummy
  int y1 = pp1 / 40, x1 = pp1 - y1 * 40;
  const char* pB1 = (const char*)(attb + (size_t)(y1 * 42 + x1) * 512) + cs * 16;

  char* ldsAb = (char*)ldsA;
  char* ldsBb = (char*)ldsB;
  int dstT = tid * 16;

#define STAGE_A(d, kh, kt)                                              \
  {                                                                     \
    int ko = (kt) * 128 + (kh) * 64;                                    \
    gll16(pA0 + ko, ldsAb + ((d) * 2 + (kh)) * 16384 + dstT);           \
    gll16(pA1 + ko, ldsAb + ((d) * 2 + (kh)) * 16384 + 8192 + dstT);    \
  }
#define STAGE_B(d, kh, kt)                                              \
  {                                                                     \
    int tp = (kt) >> 3;                                                 \
    int ty = (tp * 11) >> 5;                                            \
    int tx = tp - ty * 3;                                               \
    int ko = (ty * 42 + tx) * 1024 + ((kt) & 7) * 128 + (kh) * 64;      \
    gll16(pB0 + ko, ldsBb + ((d) * 2 + (kh)) * 16384 + dstT);           \
    gll16(pB1 + ko, ldsBb + ((d) * 2 + (kh)) * 16384 + 8192 + dstT);    \
  }
#define STAGE_U(d, kh, kt) { STAGE_A(d, kh, kt); STAGE_B(d, kh, kt); }

  // ---- compute-side lane mapping ----
  int wid = tid >> 6, lane = tid & 63;
  int wm = wid & 3, wn = wid >> 2;             // 4 o-waves x 2 p-waves
  int lrow = lane & 15, lquad = lane >> 4;
  int csel = (lquad ^ ((lrow >> 1) & 3)) << 4;
  int aBase = (wm * 64 + lrow) * 64 + csel;    // byte offset within region
  int bBase = (wn * 112 + lrow) * 64 + csel;

  const f32x4 fzero = {0.f, 0.f, 0.f, 0.f};
  f32x4 acc[4][7];
#pragma unroll
  for (int mi = 0; mi < 4; mi++)
#pragma unroll
    for (int ni = 0; ni < 7; ni++) acc[mi][ni] = fzero;

  // two fragment sets (ping-pong)
  bf16x8 fa0, fa1, fa2, fa3, fb0, fb1, fb2, fb3, fb4, fb5, fb6;
  bf16x8 ga0, ga1, ga2, ga3, gb0, gb1, gb2, gb3, gb4, gb5, gb6;

#define RD(pre, d, kh)                                                  \
  {                                                                     \
    const char* ra_ = ldsAb + ((d) * 2 + (kh)) * 16384 + aBase;         \
    const char* rb_ = ldsBb + ((d) * 2 + (kh)) * 16384 + bBase;         \
    pre##a0 = *(const bf16x8*)(ra_);                                    \
    pre##a1 = *(const bf16x8*)(ra_ + 1024);                             \
    pre##a2 = *(const bf16x8*)(ra_ + 2048);                             \
    pre##a3 = *(const bf16x8*)(ra_ + 3072);                             \
    pre##b0 = *(const bf16x8*)(rb_);                                    \
    pre##b1 = *(const bf16x8*)(rb_ + 1024);                             \
    pre##b2 = *(const bf16x8*)(rb_ + 2048);                             \
    pre##b3 = *(const bf16x8*)(rb_ + 3072);                             \
    pre##b4 = *(const bf16x8*)(rb_ + 4096);                             \
    pre##b5 = *(const bf16x8*)(rb_ + 5120);                             \
    pre##b6 = *(const bf16x8*)(rb_ + 6144);                             \
  }

#define MROW(mi, av, pre)                                                               \
  acc[mi][0] = __builtin_amdgcn_mfma_f32_16x16x32_bf16(av, pre##b0, acc[mi][0], 0, 0, 0); \
  acc[mi][1] = __builtin_amdgcn_mfma_f32_16x16x32_bf16(av, pre##b1, acc[mi][1], 0, 0, 0); \
  acc[mi][2] = __builtin_amdgcn_mfma_f32_16x16x32_bf16(av, pre##b2, acc[mi][2], 0, 0, 0); \
  acc[mi][3] = __builtin_amdgcn_mfma_f32_16x16x32_bf16(av, pre##b3, acc[mi][3], 0, 0, 0); \
  acc[mi][4] = __builtin_amdgcn_mfma_f32_16x16x32_bf16(av, pre##b4, acc[mi][4], 0, 0, 0); \
  acc[mi][5] = __builtin_amdgcn_mfma_f32_16x16x32_bf16(av, pre##b5, acc[mi][5], 0, 0, 0); \
  acc[mi][6] = __builtin_amdgcn_mfma_f32_16x16x32_bf16(av, pre##b6, acc[mi][6], 0, 0, 0);

// PHASE: stage next-next region, wait prev stage, barrier, prefetch next
// frags (rd), MFMA current frags (cp). Reads and MFMAs are independent ->
// compiler interleaves; LDS drain hides under matrix pipe.
#define PHASE(rd_d, rd_kh, rdp, cp, STG)                                       \
  {                                                                            \
    STG;                                                                       \
    asm volatile("s_waitcnt vmcnt(4)" ::: "memory");                           \
    __builtin_amdgcn_s_barrier();                                              \
    RD(rdp, rd_d, rd_kh);                                                      \
    __builtin_amdgcn_s_setprio(1);                                             \
    MROW(0, cp##a0, cp)                                                        \
    MROW(1, cp##a1, cp)                                                        \
    MROW(2, cp##a2, cp)                                                        \
    MROW(3, cp##a3, cp)                                                        \
    __builtin_amdgcn_s_setprio(0);                                             \
  }

  // ---- prologue: R0=(0,0)<-kt0, R1=(0,1)<-kt0; F <- R0 ----
  STAGE_U(0, 0, 0);
  STAGE_U(0, 1, 0);
  asm volatile("s_waitcnt vmcnt(4)" ::: "memory");  // R0 landed
  __builtin_amdgcn_s_barrier();
  RD(f, 0, 0);

#pragma unroll 1
  for (int it = 0; it < 36; ++it) {
    int kt1 = it * 2 + 1;
    int kt2 = it < 35 ? it * 2 + 2 : 71;  // clamped; garbage on last iter, unread
    PHASE(0, 1, g, f, STAGE_U(1, 0, kt1));  // P0: mfma R0(F), read R1->G
    PHASE(1, 0, f, g, STAGE_U(1, 1, kt1));  // P1: mfma R1(G), read R2->F
    PHASE(1, 1, g, f, STAGE_U(0, 0, kt2));  // P2: mfma R2(F), read R3->G
    PHASE(0, 0, f, g, STAGE_U(0, 1, kt2));  // P3: mfma R3(G), read R0->F
  }

#undef PHASE
#undef MROW
#undef RD
#undef STAGE_U
#undef STAGE_A
#undef STAGE_B

  // ---- epilogue: fp32 stores, guard pixel tail ----
#pragma unroll
  for (int mi = 0; mi < 4; mi++) {
#pragma unroll
    for (int r = 0; r < 4; r++) {
      int o = o0 + wm * 64 + mi * 16 + lquad * 4 + r;
      float* orow = outb + (size_t)o * 1600;
#pragma unroll
      for (int ni = 0; ni < 7; ni++) {
        int p = p0 + wn * 112 + ni * 16 + lrow;
        if (p < 1600) orow[p] = acc[mi][ni][r];
      }
    }
  }
}

// ---------------------------------------------------------------------------
extern "C" void kernel_launch(void* const* d_in, const int* in_sizes, int n_in,
                              void* d_out, int out_size, void* d_ws, size_t ws_size,
                              hipStream_t stream) {
  const float* ex = (const float*)d_in[0];
  const float* qu = (const float*)d_in[1];
  const float* w_e = (const float*)d_in[2];
  const float* w_q = (const float*)d_in[3];
  const float* w_c1 = (const float*)d_in[4];
  const float* w_c2 = (const float*)d_in[5];
  float* out = (float*)d_out;
  char* ws = (char*)d_ws;

  u16* E     = (u16*)(ws + 0L);            // 81,920,000
  u16* ET    = (u16*)(ws + 81920000L);     // 81,920,000
  u16* xt_e  = (u16*)(ws + 163840000L);    // 26,214,400 (reused as ebf)
  u16* xt_q  = (u16*)(ws + 190054400L);    // 26,214,400 (reused as qbf)
  u16* ecorr = (u16*)(ws + 216268800L);    // 13,107,200
  u16* qcorr = (u16*)(ws + 229376000L);    // 13,107,200
  u16* att_e = (u16*)(ws + 242483200L);    // 28,901,376
  u16* att_q = (u16*)(ws + 271384576L);    // 28,901,376
  float* Zrow = (float*)(ws + 300285952L); // 102,400
  float* Zcol = (float*)(ws + 300388352L); // 102,400
  u16* w_ebf = (u16*)(ws + 300490752L);    // 262,144
  u16* w_qbf = (u16*)(ws + 300752896L);    // 262,144
  u16* wr1   = (u16*)(ws + 301015040L);    // 4,718,592
  u16* wr2   = (u16*)(ws + 305733632L);    // 4,718,592  (total 310,452,224)

  // prep
  transp_cast_x2<<<dim3(50, 16, 32), 256, 0, stream>>>(ex, qu, xt_e, xt_q);
  cast_w<<<dim3(512), 256, 0, stream>>>(w_e, w_q, w_ebf, w_qbf);
  repack_wc<<<dim3(9216, 2), 256, 0, stream>>>(w_c1, w_c2, wr1, wr2);
  // zero att_e, att_q, Zrow, Zcol (contiguous): 58,007,552 B
  zero_mem<<<dim3(2048), 256, 0, stream>>>((uint4*)att_e, 3625472L);

  // K1: corr[b][n][o] = sum_c xt[n,c] * w[o,c]   (both e and q in one grid)
  gemm_bt64<0><<<dim3(13, 2, 32), 256, 0, stream>>>(
      xt_e, w_ebf, ecorr, xt_q, w_qbf, qcorr, 1600, 256, 512, 819200L, 0L, 409600L);

  // K2: E/ET/Zrow/Zcol fused
  gemm_corr_exp<<<dim3(13, 13, 16), 256, 0, stream>>>(ecorr, qcorr, E, ET, Zrow, Zcol);

  // K3: scale inputs by softmax denominators
  u16* ebf = xt_e;
  u16* qbf = xt_q;
  scale_div<<<dim3(51200, 2), 256, 0, stream>>>(ex, qu, Zcol, Zrow, ebf, qbf);

  // K4: att_q[p][c] = sum_i E[p,i]*ebf[c,i] ; att_e[p][c] = sum_i ET[p,i]*qbf[c,i]
  gemm_bt64<2><<<dim3(13, 4, 32), 256, 0, stream>>>(
      E, ebf, att_q, ET, qbf, att_e, 1600, 512, 1600, 2560000L, 819200L, 903168L);

  // K5: both convs, 256(o)x224(p) single-barrier 4-phase + frag prefetch
  conv_gemmpf<<<dim3(8, 2, 32), 512, 0, stream>>>(wr1, att_e, wr2, att_q, out);
}

// Round 5
// 806.139 us; speedup vs baseline: 1.1542x; 1.0308x over previous
//
#include <hip/hip_runtime.h>

typedef unsigned short u16;
typedef __attribute__((ext_vector_type(8))) short bf16x8;
typedef __attribute__((ext_vector_type(4))) float f32x4;

__device__ __forceinline__ u16 f2bf(float f) {
  union { float f; unsigned u; } v; v.f = f;
  unsigned u = v.u;
  u += 0x7fffu + ((u >> 16) & 1u);
  return (u16)(u >> 16);
}

__device__ __forceinline__ void gll16(const void* g, void* l) {
  __builtin_amdgcn_global_load_lds(
      (const __attribute__((address_space(1))) void*)g,
      (__attribute__((address_space(3))) void*)l, 16, 0, 0);
}

// ---------------------------------------------------------------------------
// P1: x[b][c][n] f32 -> xt[b][n][c] bf16   (C=512, N=1600), both inputs
// ---------------------------------------------------------------------------
__global__ __launch_bounds__(256) void transp_cast_x2(const float* __restrict__ ex,
                                                      const float* __restrict__ qu,
                                                      u16* __restrict__ xte,
                                                      u16* __restrict__ xtq) {
  __shared__ float t[32][33];
  int z = blockIdx.z;
  int b = z & 15;
  const float* xb = (z < 16 ? ex : qu) + (size_t)b * 819200;
  u16* xtb = (z < 16 ? xte : xtq) + (size_t)b * 819200;
  int n0 = blockIdx.x * 32, c0 = blockIdx.y * 32;
  int tx = threadIdx.x & 31, ty = threadIdx.x >> 5;
#pragma unroll
  for (int k = 0; k < 4; k++) {
    int c = ty + k * 8;
    t[c][tx] = xb[(size_t)(c0 + c) * 1600 + n0 + tx];
  }
  __syncthreads();
#pragma unroll
  for (int k = 0; k < 4; k++) {
    int n = ty + k * 8;
    xtb[(size_t)(n0 + n) * 512 + c0 + tx] = f2bf(t[tx][n]);
  }
}

// P2: cast w_e / w_q (256x512 each) to bf16
__global__ void cast_w(const float* __restrict__ we, const float* __restrict__ wq,
                       u16* __restrict__ oe, u16* __restrict__ oq) {
  int i = blockIdx.x * 256 + threadIdx.x;
  oe[i] = f2bf(we[i]);
  oq[i] = f2bf(wq[i]);
}

// P3: w[o][c][ky][kx] f32 -> wr[o][t*512+c] bf16 (both conv weights)
__global__ void repack_wc(const float* __restrict__ w1, const float* __restrict__ w2,
                          u16* __restrict__ o1, u16* __restrict__ o2) {
  const float* w = blockIdx.y ? w2 : w1;
  u16* wr = blockIdx.y ? o2 : o1;
  int idx = blockIdx.x * 256 + threadIdx.x;  // 2359296 total
  int o = idx / 4608;
  int r = idx - o * 4608;
  int t = r >> 9;
  int c = r & 511;
  wr[idx] = f2bf(w[o * 4608 + c * 9 + t]);
}

// P4: zero att buffers + Z buffers
__global__ void zero_mem(uint4* __restrict__ p, long n) {
  long i = (long)blockIdx.x * blockDim.x + threadIdx.x;
  long stride = (long)gridDim.x * blockDim.x;
  uint4 z; z.x = 0; z.y = 0; z.z = 0; z.w = 0;
  for (; i < n; i += stride) p[i] = z;
}

// ---------------------------------------------------------------------------
// Generic A*B^T bf16 GEMM, 128x128 tile, BK=64, XOR-swizzled LDS,
// dual problem sets selected by blockIdx.z (z<16 -> set1, else set2).
// MODE 0: store bf16 C[i*N+j].
// ---------------------------------------------------------------------------
template <int MODE>
__global__ __launch_bounds__(256) void gemm_bt64(
    const u16* __restrict__ A, const u16* __restrict__ B, u16* __restrict__ C,
    const u16* __restrict__ A2, const u16* __restrict__ B2, u16* __restrict__ C2,
    int M, int N, int K, long sA, long sB, long sC) {
  __shared__ u16 lds_a[128 * 64];
  __shared__ u16 lds_b[128 * 64];
  int tid = threadIdx.x;
  int z = blockIdx.z, b = z & 15;
  const u16* Ab = (z < 16 ? A : A2) + (size_t)b * sA;
  const u16* Bb = (z < 16 ? B : B2) + (size_t)b * sB;
  u16* Cb = (z < 16 ? C : C2) + (size_t)b * sC;
  int m0 = blockIdx.x * 128, n0 = blockIdx.y * 128;

  int rsub = tid >> 3;                     // 0..31
  int gch = (tid & 7) ^ (rsub & 7);        // swizzled 16B chunk to fetch
  long Kb = (long)K * 2;
  const char* pa[4];
  const char* pb[4];
#pragma unroll
  for (int c = 0; c < 4; c++) {
    int ra = m0 + 32 * c + rsub; ra = ra < M ? ra : M - 1;
    int rb = n0 + 32 * c + rsub; rb = rb < N ? rb : N - 1;
    pa[c] = (const char*)Ab + (long)ra * Kb + gch * 16;
    pb[c] = (const char*)Bb + (long)rb * Kb + gch * 16;
  }

  const f32x4 fzero = {0.f, 0.f, 0.f, 0.f};
  f32x4 acc[4][4];
#pragma unroll
  for (int mi = 0; mi < 4; mi++)
#pragma unroll
    for (int ni = 0; ni < 4; ni++) acc[mi][ni] = fzero;

  int wid = tid >> 6, lane = tid & 63;
  int wm = wid & 1, wn = wid >> 1;
  int lrow = lane & 15, lquad = lane >> 4;
  int sl = lrow & 7;

  int ksteps = K >> 6;
  for (int ks = 0; ks < ksteps; ks++) {
#pragma unroll
    for (int c = 0; c < 4; c++) {
      gll16(pa[c], (char*)lds_a + c * 4096 + tid * 16);
      gll16(pb[c], (char*)lds_b + c * 4096 + tid * 16);
      pa[c] += 128; pb[c] += 128;
    }
    __syncthreads();
#pragma unroll
    for (int k2 = 0; k2 < 2; k2++) {
      int sel = ((k2 << 2) | lquad) ^ sl;
      bf16x8 bv[4];
#pragma unroll
      for (int ni = 0; ni < 4; ni++) {
        int rowb = wn * 64 + ni * 16 + lrow;
        bv[ni] = *(const bf16x8*)((const char*)lds_b + rowb * 128 + sel * 16);
      }
#pragma unroll
      for (int mi = 0; mi < 4; mi++) {
        int rowa = wm * 64 + mi * 16 + lrow;
        bf16x8 av = *(const bf16x8*)((const char*)lds_a + rowa * 128 + sel * 16);
#pragma unroll
        for (int ni = 0; ni < 4; ni++)
          acc[mi][ni] =
              __builtin_amdgcn_mfma_f32_16x16x32_bf16(av, bv[ni], acc[mi][ni], 0, 0, 0);
      }
    }
    __syncthreads();
  }

#pragma unroll
  for (int mi = 0; mi < 4; mi++) {
#pragma unroll
    for (int r = 0; r < 4; r++) {
      int i = m0 + wm * 64 + mi * 16 + lquad * 4 + r;
      if (i >= M) continue;
#pragma unroll
      for (int ni = 0; ni < 4; ni++) {
        int j = n0 + wn * 64 + ni * 16 + lrow;
        if (j >= N) continue;
        Cb[(size_t)i * N + j] = f2bf(acc[mi][ni][r]);
      }
    }
  }
}

// ---------------------------------------------------------------------------
// K2: E = exp(ecorr * qcorr^T)  [1600x1600 per batch, K=256]
// Fused epilogue: E (coalesced 16B rows), ET (LDS transpose), Zrow/Zcol sums
// via shuffle + atomics.
// ---------------------------------------------------------------------------
__global__ __launch_bounds__(256) void gemm_corr_exp(
    const u16* __restrict__ A, const u16* __restrict__ B, u16* __restrict__ E,
    u16* __restrict__ ET, float* __restrict__ Zrow, float* __restrict__ Zcol) {
  __shared__ u16 lds_a[128 * 64];
  __shared__ u16 lds_b[128 * 64];
  int tid = threadIdx.x;
  int b = blockIdx.z;
  const u16* Ab = A + (size_t)b * 409600;
  const u16* Bb = B + (size_t)b * 409600;
  u16* Eb = E + (size_t)b * 2560000;
  u16* ETb = ET + (size_t)b * 2560000;
  int m0 = blockIdx.x * 128, n0 = blockIdx.y * 128;

  int rsub = tid >> 3;
  int gch = (tid & 7) ^ (rsub & 7);
  const char* pa[4];
  const char* pb[4];
#pragma unroll
  for (int c = 0; c < 4; c++) {
    int ra = m0 + 32 * c + rsub; ra = ra < 1600 ? ra : 1599;
    int rb = n0 + 32 * c + rsub; rb = rb < 1600 ? rb : 1599;
    pa[c] = (const char*)(Ab + (size_t)ra * 256) + gch * 16;
    pb[c] = (const char*)(Bb + (size_t)rb * 256) + gch * 16;
  }

  const f32x4 fzero = {0.f, 0.f, 0.f, 0.f};
  f32x4 acc[4][4];
#pragma unroll
  for (int mi = 0; mi < 4; mi++)
#pragma unroll
    for (int ni = 0; ni < 4; ni++) acc[mi][ni] = fzero;

  int wid = tid >> 6, lane = tid & 63;
  int wm = wid & 1, wn = wid >> 1;
  int lrow = lane & 15, lquad = lane >> 4;
  int sl = lrow & 7;

  for (int ks = 0; ks < 4; ks++) {
#pragma unroll
    for (int c = 0; c < 4; c++) {
      gll16(pa[c], (char*)lds_a + c * 4096 + tid * 16);
      gll16(pb[c], (char*)lds_b + c * 4096 + tid * 16);
      pa[c] += 128; pb[c] += 128;
    }
    __syncthreads();
#pragma unroll
    for (int k2 = 0; k2 < 2; k2++) {
      int sel = ((k2 << 2) | lquad) ^ sl;
      bf16x8 bv[4];
#pragma unroll
      for (int ni = 0; ni < 4; ni++) {
        int rowb = wn * 64 + ni * 16 + lrow;
        bv[ni] = *(const bf16x8*)((const char*)lds_b + rowb * 128 + sel * 16);
      }
#pragma unroll
      for (int mi = 0; mi < 4; mi++) {
        int rowa = wm * 64 + mi * 16 + lrow;
        bf16x8 av = *(const bf16x8*)((const char*)lds_a + rowa * 128 + sel * 16);
#pragma unroll
        for (int ni = 0; ni < 4; ni++)
          acc[mi][ni] =
              __builtin_amdgcn_mfma_f32_16x16x32_bf16(av, bv[ni], acc[mi][ni], 0, 0, 0);
      }
    }
    __syncthreads();
  }

  // ---- fused epilogue: exp, E store, ET store (LDS transpose), Z sums ----
  const int TS = 136;  // padded LDS row stride (u16) for 32x128 slice
  u16* T = lds_a;
  float colacc[4] = {0.f, 0.f, 0.f, 0.f};
#pragma unroll
  for (int s = 0; s < 4; s++) {
    if (wm == (s >> 1)) {
      int smi0 = (s & 1) * 2;
#pragma unroll
      for (int mi2 = 0; mi2 < 2; mi2++) {
        int mi = smi0 + mi2;
        float rowp[4] = {0.f, 0.f, 0.f, 0.f};
#pragma unroll
        for (int ni = 0; ni < 4; ni++) {
          int j = n0 + wn * 64 + ni * 16 + lrow;
          bool jv = j < 1600;
#pragma unroll
          for (int r = 0; r < 4; r++) {
            int i = m0 + wm * 64 + mi * 16 + lquad * 4 + r;
            float e = __expf(acc[mi][ni][r]);
            T[(mi2 * 16 + lquad * 4 + r) * TS + wn * 64 + ni * 16 + lrow] = f2bf(e);
            rowp[r] += jv ? e : 0.f;
            colacc[ni] += (i < 1600) ? e : 0.f;
          }
        }
#pragma unroll
        for (int r = 0; r < 4; r++) {
          float v = rowp[r];
          v += __shfl_xor(v, 1);
          v += __shfl_xor(v, 2);
          v += __shfl_xor(v, 4);
          v += __shfl_xor(v, 8);
          int i = m0 + wm * 64 + mi * 16 + lquad * 4 + r;
          if (lrow == 0 && i < 1600) atomicAdd(&Zrow[b * 1600 + i], v);
        }
      }
    }
    __syncthreads();
    // E rows: 32 rows x 128 cols, 16B coalesced stores
#pragma unroll
    for (int p = 0; p < 2; p++) {
      int jj = tid + p * 256;
      int ml = jj >> 4, n8 = jj & 15;
      int gi = m0 + s * 32 + ml, gj = n0 + n8 * 8;
      if (gi < 1600 && gj < 1600)
        *(uint4*)(Eb + (size_t)gi * 1600 + gj) = *(const uint4*)&T[ml * TS + n8 * 8];
    }
    // ET rows: transposed, 8B stores
#pragma unroll
    for (int p = 0; p < 4; p++) {
      int jj = tid + p * 256;
      int n = jj >> 3, m4 = jj & 7;
      int gm = m0 + s * 32 + m4 * 4, gn = n0 + n;
      if (gn < 1600 && gm < 1600) {
        ushort4 v;
        v.x = T[(m4 * 4 + 0) * TS + n];
        v.y = T[(m4 * 4 + 1) * TS + n];
        v.z = T[(m4 * 4 + 2) * TS + n];
        v.w = T[(m4 * 4 + 3) * TS + n];
        *(ushort4*)(ETb + (size_t)gn * 1600 + gm) = v;
      }
    }
    __syncthreads();
  }
#pragma unroll
  for (int ni = 0; ni < 4; ni++) {
    float v = colacc[ni];
    v += __shfl_xor(v, 16);
    v += __shfl_xor(v, 32);
    int j = n0 + wn * 64 + ni * 16 + lrow;
    if (lquad == 0 && j < 1600) atomicAdd(&Zcol[b * 1600 + j], v);
  }
}

// K3: out[idx] = bf16( x[idx] / Z[b][pixel] )   (both inputs via blockIdx.y)
__global__ void scale_div(const float* __restrict__ ex, const float* __restrict__ qu,
                          const float* __restrict__ Zcol, const float* __restrict__ Zrow,
                          u16* __restrict__ ebf, u16* __restrict__ qbf) {
  const float* x; const float* Z; u16* o;
  if (blockIdx.y == 0) { x = ex; Z = Zcol; o = ebf; }
  else { x = qu; Z = Zrow; o = qbf; }
  size_t idx = (size_t)blockIdx.x * 256 + threadIdx.x;  // 13,107,200
  int b = (int)(idx / 819200);
  int i = (int)(idx % 1600);
  o[idx] = f2bf(x[idx] / Z[b * 1600 + i]);
}

// ---------------------------------------------------------------------------
// K4: att GEMMs in the K5 template. 256(c)x224(p) tile, single-barrier
// phases + frag prefetch + counted vmcnt. A = proj (512 x 1600 K-major),
// B = E/ET pixel rows (1600 x 1600), C -> padded pixel layout bf16.
// K = 1600 = 25 k-tiles: 12 double-k iterations + 2-phase tail.
// z-chunked XCD swizzle: all 16 blocks of one batch land on one XCD so the
// per-z working set (E 5.1MB + proj 1.6MB) is fetched ~once per XCD.
// ---------------------------------------------------------------------------
__global__ __launch_bounds__(512, 2) void att_gemmpf(
    const u16* __restrict__ Aw1, const u16* __restrict__ Bp1, u16* __restrict__ C1,
    const u16* __restrict__ Aw2, const u16* __restrict__ Bp2, u16* __restrict__ C2) {
  __shared__ u16 ldsA[32768];  // [2][2][256 rows][32 elems]
  __shared__ u16 ldsB[32768];  // rows 224+ dummy
  int tid = threadIdx.x;
  // z-chunked XCD swizzle over 512 blocks
  int flat = blockIdx.x + (blockIdx.y << 3) + (blockIdx.z << 4);
  int wrk = (flat & 7) * 64 + (flat >> 3);
  int z = wrk >> 4, rr = wrk & 15;
  int bx = rr & 7, by = rr >> 3;
  int b = z & 15;
  const u16* Aw = (z < 16 ? Aw1 : Aw2) + (size_t)b * 819200;
  const u16* Bp = (z < 16 ? Bp1 : Bp2) + (size_t)b * 2560000;
  u16* Cb = (z < 16 ? C1 : C2) + (size_t)b * 903168;
  int p0 = bx * 224, o0 = by * 256;

  // ---- staging setup (source pre-swizzle, linear LDS dest) ----
  int rl = tid >> 2;                      // local row 0..127 (second call +128)
  int cs = (tid & 3) ^ ((rl >> 1) & 3);   // swizzled 16B source chunk (of 4)
  const char* pA0 = (const char*)(Aw + (size_t)(o0 + rl) * 1600) + cs * 16;
  const char* pA1 = pA0 + 128 * 3200;
  int pp0 = p0 + rl; pp0 = pp0 < 1600 ? pp0 : 1599;
  const char* pB0 = (const char*)(Bp + (size_t)pp0 * 1600) + cs * 16;
  int pp1 = p0 + 128 + rl; pp1 = pp1 < 1600 ? pp1 : 1599;  // rows 224+ dummy
  const char* pB1 = (const char*)(Bp + (size_t)pp1 * 1600) + cs * 16;

  char* ldsAb = (char*)ldsA;
  char* ldsBb = (char*)ldsB;
  int dstT = tid * 16;

#define STAGE_U(d, kh, kt)                                              \
  {                                                                     \
    int ko = (kt) * 128 + (kh) * 64;                                    \
    gll16(pA0 + ko, ldsAb + ((d) * 2 + (kh)) * 16384 + dstT);           \
    gll16(pA1 + ko, ldsAb + ((d) * 2 + (kh)) * 16384 + 8192 + dstT);    \
    gll16(pB0 + ko, ldsBb + ((d) * 2 + (kh)) * 16384 + dstT);           \
    gll16(pB1 + ko, ldsBb + ((d) * 2 + (kh)) * 16384 + 8192 + dstT);    \
  }

  // ---- compute-side lane mapping ----
  int wid = tid >> 6, lane = tid & 63;
  int wm = wid & 3, wn = wid >> 2;             // 4 c-waves x 2 p-waves
  int lrow = lane & 15, lquad = lane >> 4;
  int csel = (lquad ^ ((lrow >> 1) & 3)) << 4;
  int aBase = (wm * 64 + lrow) * 64 + csel;
  int bBase = (wn * 112 + lrow) * 64 + csel;

  const f32x4 fzero = {0.f, 0.f, 0.f, 0.f};
  f32x4 acc[4][7];
#pragma unroll
  for (int mi = 0; mi < 4; mi++)
#pragma unroll
    for (int ni = 0; ni < 7; ni++) acc[mi][ni] = fzero;

  bf16x8 fa0, fa1, fa2, fa3, fb0, fb1, fb2, fb3, fb4, fb5, fb6;
  bf16x8 ga0, ga1, ga2, ga3, gb0, gb1, gb2, gb3, gb4, gb5, gb6;

#define RD(pre, d, kh)                                                  \
  {                                                                     \
    const char* ra_ = ldsAb + ((d) * 2 + (kh)) * 16384 + aBase;         \
    const char* rb_ = ldsBb + ((d) * 2 + (kh)) * 16384 + bBase;         \
    pre##a0 = *(const bf16x8*)(ra_);                                    \
    pre##a1 = *(const bf16x8*)(ra_ + 1024);                             \
    pre##a2 = *(const bf16x8*)(ra_ + 2048);                             \
    pre##a3 = *(const bf16x8*)(ra_ + 3072);                             \
    pre##b0 = *(const bf16x8*)(rb_);                                    \
    pre##b1 = *(const bf16x8*)(rb_ + 1024);                             \
    pre##b2 = *(const bf16x8*)(rb_ + 2048);                             \
    pre##b3 = *(const bf16x8*)(rb_ + 3072);                             \
    pre##b4 = *(const bf16x8*)(rb_ + 4096);                             \
    pre##b5 = *(const bf16x8*)(rb_ + 5120);                             \
    pre##b6 = *(const bf16x8*)(rb_ + 6144);                             \
  }

#define MROW(mi, av, pre)                                                               \
  acc[mi][0] = __builtin_amdgcn_mfma_f32_16x16x32_bf16(av, pre##b0, acc[mi][0], 0, 0, 0); \
  acc[mi][1] = __builtin_amdgcn_mfma_f32_16x16x32_bf16(av, pre##b1, acc[mi][1], 0, 0, 0); \
  acc[mi][2] = __builtin_amdgcn_mfma_f32_16x16x32_bf16(av, pre##b2, acc[mi][2], 0, 0, 0); \
  acc[mi][3] = __builtin_amdgcn_mfma_f32_16x16x32_bf16(av, pre##b3, acc[mi][3], 0, 0, 0); \
  acc[mi][4] = __builtin_amdgcn_mfma_f32_16x16x32_bf16(av, pre##b4, acc[mi][4], 0, 0, 0); \
  acc[mi][5] = __builtin_amdgcn_mfma_f32_16x16x32_bf16(av, pre##b5, acc[mi][5], 0, 0, 0); \
  acc[mi][6] = __builtin_amdgcn_mfma_f32_16x16x32_bf16(av, pre##b6, acc[mi][6], 0, 0, 0);

#define PHASE(rd_d, rd_kh, rdp, cp, STG)                                       \
  {                                                                            \
    STG;                                                                       \
    asm volatile("s_waitcnt vmcnt(4)" ::: "memory");                           \
    __builtin_amdgcn_s_barrier();                                              \
    RD(rdp, rd_d, rd_kh);                                                      \
    __builtin_amdgcn_s_setprio(1);                                             \
    MROW(0, cp##a0, cp)                                                        \
    MROW(1, cp##a1, cp)                                                        \
    MROW(2, cp##a2, cp)                                                        \
    MROW(3, cp##a3, cp)                                                        \
    __builtin_amdgcn_s_setprio(0);                                             \
  }

  // ---- prologue: R0=(0,0)<-kt0, R1=(0,1)<-kt0; F <- R0 ----
  STAGE_U(0, 0, 0);
  STAGE_U(0, 1, 0);
  asm volatile("s_waitcnt vmcnt(4)" ::: "memory");  // R0 landed
  __builtin_amdgcn_s_barrier();
  RD(f, 0, 0);

#pragma unroll 1
  for (int it = 0; it < 12; ++it) {
    int kt1 = it * 2 + 1;
    int kt2 = it * 2 + 2;  // <= 24
    PHASE(0, 1, g, f, STAGE_U(1, 0, kt1));  // mfma kt0.k0, read kt0.k1
    PHASE(1, 0, f, g, STAGE_U(1, 1, kt1));  // mfma kt0.k1, read kt1.k0
    PHASE(1, 1, g, f, STAGE_U(0, 0, kt2));  // mfma kt1.k0, read kt1.k1
    PHASE(0, 0, f, g, STAGE_U(0, 1, kt2));  // mfma kt1.k1, read kt2.k0
  }
  // ---- tail: kt=24 lives in R0,R1; f holds R0 frags ----
  asm volatile("s_waitcnt vmcnt(0)" ::: "memory");  // R1 stage landed
  __builtin_amdgcn_s_barrier();
  RD(g, 0, 1);
  __builtin_amdgcn_s_setprio(1);
  MROW(0, fa0, f) MROW(1, fa1, f) MROW(2, fa2, f) MROW(3, fa3, f)
  MROW(0, ga0, g) MROW(1, ga1, g) MROW(2, ga2, g) MROW(3, ga3, g)
  __builtin_amdgcn_s_setprio(0);

#undef PHASE
#undef MROW
#undef RD
#undef STAGE_U

  // ---- epilogue: bf16 stores to padded pixel layout ----
#pragma unroll
  for (int mi = 0; mi < 4; mi++) {
#pragma unroll
    for (int r = 0; r < 4; r++) {
      int o = o0 + wm * 64 + mi * 16 + lquad * 4 + r;
#pragma unroll
      for (int ni = 0; ni < 7; ni++) {
        int p = p0 + wn * 112 + ni * 16 + lrow;
        if (p < 1600) {
          int y = p / 40, x = p - y * 40;
          Cb[(size_t)((y + 1) * 42 + (x + 1)) * 512 + o] = f2bf(acc[mi][ni][r]);
        }
      }
    }
  }
}

// ---------------------------------------------------------------------------
// K5: both 3x3 convs, 256(o)x224(p) tile, single-barrier 4-phase +
// fragment prefetch. (Validated round 4: 244 us, unchanged this round.)
// ---------------------------------------------------------------------------
__global__ __launch_bounds__(512, 2) void conv_gemmpf(
    const u16* __restrict__ W1, const u16* __restrict__ ATT1,
    const u16* __restrict__ W2, const u16* __restrict__ ATT2,
    float* __restrict__ out) {
  __shared__ u16 ldsA[32768];  // [2][2][256 rows][32 elems]
  __shared__ u16 ldsB[32768];  // rows 224+ dummy
  int tid = threadIdx.x;
  int z = blockIdx.z, b = z & 15, sel2 = z >> 4;
  const u16* W = sel2 ? W2 : W1;
  const u16* attb = (sel2 ? ATT2 : ATT1) + (size_t)b * 903168;
  float* outb = out + (size_t)b * 1638400 + (size_t)(sel2 ? 512 : 0) * 1600;
  int p0 = blockIdx.x * 224, o0 = blockIdx.y * 256;

  int rl = tid >> 2;
  int cs = (tid & 3) ^ ((rl >> 1) & 3);
  const char* pA0 = (const char*)(W + (size_t)(o0 + rl) * 4608) + cs * 16;
  const char* pA1 = pA0 + 128 * 9216;
  int pp0 = p0 + rl; pp0 = pp0 < 1600 ? pp0 : 1599;
  int y0 = pp0 / 40, x0 = pp0 - y0 * 40;
  const char* pB0 = (const char*)(attb + (size_t)(y0 * 42 + x0) * 512) + cs * 16;
  int pp1 = p0 + 128 + rl; pp1 = pp1 < 1600 ? pp1 : 1599;
  int y1 = pp1 / 40, x1 = pp1 - y1 * 40;
  const char* pB1 = (const char*)(attb + (size_t)(y1 * 42 + x1) * 512) + cs * 16;

  char* ldsAb = (char*)ldsA;
  char* ldsBb = (char*)ldsB;
  int dstT = tid * 16;

#define STAGE_A(d, kh, kt)                                              \
  {                                                                     \
    int ko = (kt) * 128 + (kh) * 64;                                    \
    gll16(pA0 + ko, ldsAb + ((d) * 2 + (kh)) * 16384 + dstT);           \
    gll16(pA1 + ko, ldsAb + ((d) * 2 + (kh)) * 16384 + 8192 + dstT);    \
  }
#define STAGE_B(d, kh, kt)                                              \
  {                                                                     \
    int tp = (kt) >> 3;                                                 \
    int ty = (tp * 11) >> 5;                                            \
    int tx = tp - ty * 3;                                               \
    int ko = (ty * 42 + tx) * 1024 + ((kt) & 7) * 128 + (kh) * 64;      \
    gll16(pB0 + ko, ldsBb + ((d) * 2 + (kh)) * 16384 + dstT);           \
    gll16(pB1 + ko, ldsBb + ((d) * 2 + (kh)) * 16384 + 8192 + dstT);    \
  }
#define STAGE_U(d, kh, kt) { STAGE_A(d, kh, kt); STAGE_B(d, kh, kt); }

  int wid = tid >> 6, lane = tid & 63;
  int wm = wid & 3, wn = wid >> 2;
  int lrow = lane & 15, lquad = lane >> 4;
  int csel = (lquad ^ ((lrow >> 1) & 3)) << 4;
  int aBase = (wm * 64 + lrow) * 64 + csel;
  int bBase = (wn * 112 + lrow) * 64 + csel;

  const f32x4 fzero = {0.f, 0.f, 0.f, 0.f};
  f32x4 acc[4][7];
#pragma unroll
  for (int mi = 0; mi < 4; mi++)
#pragma unroll
    for (int ni = 0; ni < 7; ni++) acc[mi][ni] = fzero;

  bf16x8 fa0, fa1, fa2, fa3, fb0, fb1, fb2, fb3, fb4, fb5, fb6;
  bf16x8 ga0, ga1, ga2, ga3, gb0, gb1, gb2, gb3, gb4, gb5, gb6;

#define RD(pre, d, kh)                                                  \
  {                                                                     \
    const char* ra_ = ldsAb + ((d) * 2 + (kh)) * 16384 + aBase;         \
    const char* rb_ = ldsBb + ((d) * 2 + (kh)) * 16384 + bBase;         \
    pre##a0 = *(const bf16x8*)(ra_);                                    \
    pre##a1 = *(const bf16x8*)(ra_ + 1024);                             \
    pre##a2 = *(const bf16x8*)(ra_ + 2048);                             \
    pre##a3 = *(const bf16x8*)(ra_ + 3072);                             \
    pre##b0 = *(const bf16x8*)(rb_);                                    \
    pre##b1 = *(const bf16x8*)(rb_ + 1024);                             \
    pre##b2 = *(const bf16x8*)(rb_ + 2048);                             \
    pre##b3 = *(const bf16x8*)(rb_ + 3072);                             \
    pre##b4 = *(const bf16x8*)(rb_ + 4096);                             \
    pre##b5 = *(const bf16x8*)(rb_ + 5120);                             \
    pre##b6 = *(const bf16x8*)(rb_ + 6144);                             \
  }

#define MROW(mi, av, pre)                                                               \
  acc[mi][0] = __builtin_amdgcn_mfma_f32_16x16x32_bf16(av, pre##b0, acc[mi][0], 0, 0, 0); \
  acc[mi][1] = __builtin_amdgcn_mfma_f32_16x16x32_bf16(av, pre##b1, acc[mi][1], 0, 0, 0); \
  acc[mi][2] = __builtin_amdgcn_mfma_f32_16x16x32_bf16(av, pre##b2, acc[mi][2], 0, 0, 0); \
  acc[mi][3] = __builtin_amdgcn_mfma_f32_16x16x32_bf16(av, pre##b3, acc[mi][3], 0, 0, 0); \
  acc[mi][4] = __builtin_amdgcn_mfma_f32_16x16x32_bf16(av, pre##b4, acc[mi][4], 0, 0, 0); \
  acc[mi][5] = __builtin_amdgcn_mfma_f32_16x16x32_bf16(av, pre##b5, acc[mi][5], 0, 0, 0); \
  acc[mi][6] = __builtin_amdgcn_mfma_f32_16x16x32_bf16(av, pre##b6, acc[mi][6], 0, 0, 0);

#define PHASE(rd_d, rd_kh, rdp, cp, STG)                                       \
  {                                                                            \
    STG;                                                                       \
    asm volatile("s_waitcnt vmcnt(4)" ::: "memory");                           \
    __builtin_amdgcn_s_barrier();                                              \
    RD(rdp, rd_d, rd_kh);                                                      \
    __builtin_amdgcn_s_setprio(1);                                             \
    MROW(0, cp##a0, cp)                                                        \
    MROW(1, cp##a1, cp)                                                        \
    MROW(2, cp##a2, cp)                                                        \
    MROW(3, cp##a3, cp)                                                        \
    __builtin_amdgcn_s_setprio(0);                                             \
  }

  STAGE_U(0, 0, 0);
  STAGE_U(0, 1, 0);
  asm volatile("s_waitcnt vmcnt(4)" ::: "memory");
  __builtin_amdgcn_s_barrier();
  RD(f, 0, 0);

#pragma unroll 1
  for (int it = 0; it < 36; ++it) {
    int kt1 = it * 2 + 1;
    int kt2 = it < 35 ? it * 2 + 2 : 71;  // clamped; garbage on last iter, unread
    PHASE(0, 1, g, f, STAGE_U(1, 0, kt1));
    PHASE(1, 0, f, g, STAGE_U(1, 1, kt1));
    PHASE(1, 1, g, f, STAGE_U(0, 0, kt2));
    PHASE(0, 0, f, g, STAGE_U(0, 1, kt2));
  }

#undef PHASE
#undef MROW
#undef RD
#undef STAGE_U
#undef STAGE_A
#undef STAGE_B

#pragma unroll
  for (int mi = 0; mi < 4; mi++) {
#pragma unroll
    for (int r = 0; r < 4; r++) {
      int o = o0 + wm * 64 + mi * 16 + lquad * 4 + r;
      float* orow = outb + (size_t)o * 1600;
#pragma unroll
      for (int ni = 0; ni < 7; ni++) {
        int p = p0 + wn * 112 + ni * 16 + lrow;
        if (p < 1600) orow[p] = acc[mi][ni][r];
      }
    }
  }
}

// ---------------------------------------------------------------------------
extern "C" void kernel_launch(void* const* d_in, const int* in_sizes, int n_in,
                              void* d_out, int out_size, void* d_ws, size_t ws_size,
                              hipStream_t stream) {
  const float* ex = (const float*)d_in[0];
  const float* qu = (const float*)d_in[1];
  const float* w_e = (const float*)d_in[2];
  const float* w_q = (const float*)d_in[3];
  const float* w_c1 = (const float*)d_in[4];
  const float* w_c2 = (const float*)d_in[5];
  float* out = (float*)d_out;
  char* ws = (char*)d_ws;

  u16* E     = (u16*)(ws + 0L);            // 81,920,000
  u16* ET    = (u16*)(ws + 81920000L);     // 81,920,000
  u16* xt_e  = (u16*)(ws + 163840000L);    // 26,214,400 (reused as ebf)
  u16* xt_q  = (u16*)(ws + 190054400L);    // 26,214,400 (reused as qbf)
  u16* ecorr = (u16*)(ws + 216268800L);    // 13,107,200
  u16* qcorr = (u16*)(ws + 229376000L);    // 13,107,200
  u16* att_e = (u16*)(ws + 242483200L);    // 28,901,376
  u16* att_q = (u16*)(ws + 271384576L);    // 28,901,376
  float* Zrow = (float*)(ws + 300285952L); // 102,400
  float* Zcol = (float*)(ws + 300388352L); // 102,400
  u16* w_ebf = (u16*)(ws + 300490752L);    // 262,144
  u16* w_qbf = (u16*)(ws + 300752896L);    // 262,144
  u16* wr1   = (u16*)(ws + 301015040L);    // 4,718,592
  u16* wr2   = (u16*)(ws + 305733632L);    // 4,718,592  (total 310,452,224)

  // prep
  transp_cast_x2<<<dim3(50, 16, 32), 256, 0, stream>>>(ex, qu, xt_e, xt_q);
  cast_w<<<dim3(512), 256, 0, stream>>>(w_e, w_q, w_ebf, w_qbf);
  repack_wc<<<dim3(9216, 2), 256, 0, stream>>>(w_c1, w_c2, wr1, wr2);
  // zero att_e, att_q, Zrow, Zcol (contiguous): 58,007,552 B
  zero_mem<<<dim3(2048), 256, 0, stream>>>((uint4*)att_e, 3625472L);

  // K1: corr[b][n][o] = sum_c xt[n,c] * w[o,c]   (both e and q in one grid)
  gemm_bt64<0><<<dim3(13, 2, 32), 256, 0, stream>>>(
      xt_e, w_ebf, ecorr, xt_q, w_qbf, qcorr, 1600, 256, 512, 819200L, 0L, 409600L);

  // K2: E/ET/Zrow/Zcol fused
  gemm_corr_exp<<<dim3(13, 13, 16), 256, 0, stream>>>(ecorr, qcorr, E, ET, Zrow, Zcol);

  // K3: scale inputs by softmax denominators
  u16* ebf = xt_e;
  u16* qbf = xt_q;
  scale_div<<<dim3(51200, 2), 256, 0, stream>>>(ex, qu, Zcol, Zrow, ebf, qbf);

  // K4: att_q[p][c] = sum_i E[p,i]*ebf[c,i] ; att_e[p][c] = sum_i ET[p,i]*qbf[c,i]
  att_gemmpf<<<dim3(8, 2, 32), 512, 0, stream>>>(ebf, E, att_q, qbf, ET, att_e);

  // K5: both convs, 256(o)x224(p) single-barrier 4-phase + frag prefetch
  conv_gemmpf<<<dim3(8, 2, 32), 512, 0, stream>>>(wr1, att_e, wr2, att_q, out);
}